// Round 11
// baseline (241.729 us; speedup 1.0000x reference)
//
#include <hip/hip_runtime.h>
#include <hip/hip_cooperative_groups.h>
#include <math.h>

#define BB 32
#define SS 128
#define DIN 16
#define HH 128
#define NBSH (BB*SS*HH)   // 524288

typedef __attribute__((ext_vector_type(8))) short short8;
typedef __attribute__((ext_vector_type(4))) float vf4;

__device__ __forceinline__ float4 f4fma(float s, float4 w, float4 c){
    return make_float4(fmaf(s,w.x,c.x), fmaf(s,w.y,c.y), fmaf(s,w.z,c.z), fmaf(s,w.w,c.w));
}
__device__ __forceinline__ unsigned short f2bf(float x){
    union { float f; unsigned int u; } v; v.f = x;
    unsigned int r = v.u + 0x7FFF + ((v.u >> 16) & 1);
    return (unsigned short)(r >> 16);
}
__device__ __forceinline__ float bf2f(unsigned short b){
    union { unsigned int u; float f; } v; v.u = ((unsigned int)b) << 16;
    return v.f;
}

// ============ K0: prep — composite conv weights + wl/wr transposed bf16 splits =
__global__ __launch_bounds__(256) void k_prep(
    const float* __restrict__ w12, const float* __restrict__ w22,
    const float* __restrict__ w31,
    const float* __restrict__ w11, const float* __restrict__ b11,
    const float* __restrict__ w21, const float* __restrict__ b21,
    const float* __restrict__ wl, const float* __restrict__ wr,
    float* __restrict__ W3, float* __restrict__ W5, float* __restrict__ W31T,
    float* __restrict__ Beff1, float* __restrict__ Beff2, float* __restrict__ accf,
    unsigned short* __restrict__ wHi, unsigned short* __restrict__ wLo)
{
    __shared__ float W12L[8*384];
    __shared__ float W22L[8*640];
    __shared__ float w11L[2048], w21L[2048], b11L[128], b21L[128];
    int blk = blockIdx.x; int tid = threadIdx.x;

    if (blk < 16){
        int h0 = blk*8;
        for (int i = tid; i < 768; i += 256){
            int hl = i/96, o4 = i%96;
            *reinterpret_cast<float4*>(W12L + hl*384 + o4*4) =
                reinterpret_cast<const float4*>(w12)[(h0+hl)*96 + o4];
        }
        for (int i = tid; i < 1280; i += 256){
            int hl = i/160, o4 = i%160;
            *reinterpret_cast<float4*>(W22L + hl*640 + o4*4) =
                reinterpret_cast<const float4*>(w22)[(h0+hl)*160 + o4];
        }
        for (int i = tid; i < 512; i += 256)
            *reinterpret_cast<float4*>(w11L + i*4) = reinterpret_cast<const float4*>(w11)[i];
        for (int i = tid; i < 512; i += 256)
            *reinterpret_cast<float4*>(w21L + i*4) = reinterpret_cast<const float4*>(w21)[i];
        if (tid < 128){ b11L[tid] = b11[tid]; b21L[tid] = b21[tid]; }
        if (blk == 0){ for (int i = tid; i < 768; i += 256) accf[i] = 0.f; }
        __syncthreads();

        for (int T = tid; T < 1216; T += 256){
            if (T < 384){
                int hl = T/48, kd = T%48, k = kd>>4, d = kd&15;
                float a = 0.f;
                #pragma unroll 4
                for (int c = 0; c < HH; ++c) a = fmaf(W12L[hl*384 + c*3 + k], w11L[c*16 + d], a);
                W3[(k*16+d)*128 + h0+hl] = a;
            } else if (T < 1024){
                int tt = T-384, hl = tt/80, kd = tt%80, k = kd>>4, d = kd&15;
                float a = 0.f;
                #pragma unroll 4
                for (int c = 0; c < HH; ++c) a = fmaf(W22L[hl*640 + c*5 + k], w21L[c*16 + d], a);
                W5[(k*16+d)*128 + h0+hl] = a;
            } else if (T < 1048){
                int tt = T-1024, hl = tt/3, k = tt%3;
                float a = 0.f;
                #pragma unroll 4
                for (int c = 0; c < HH; ++c) a = fmaf(W12L[hl*384 + c*3 + k], b11L[c], a);
                Beff1[k*128 + h0+hl] = a;
            } else if (T < 1088){
                int tt = T-1048, hl = tt/5, k = tt%5;
                float a = 0.f;
                #pragma unroll 4
                for (int c = 0; c < HH; ++c) a = fmaf(W22L[hl*640 + c*5 + k], b21L[c], a);
                Beff2[k*128 + h0+hl] = a;
            } else {
                int tt = T-1088, hl = tt>>4, d = tt&15;
                W31T[d*128 + h0+hl] = w31[(h0+hl)*16 + d];
            }
        }
    } else {
        int q = blk - 16;          // 0..23
        int h = tid & 127; int half = tid >> 7;
        for (int rl = half; rl < 32; rl += 2){
            int r = q*32 + rl;     // 0..767
            int m = r >> 7;
            int c = r & 127;
            const float* src = (m < 3) ? (wl + (size_t)m*16384) : (wr + (size_t)(m-3)*16384);
            float v = src[c*128 + h];
            unsigned short hi = f2bf(v);
            unsigned short lo = f2bf(v - bf2f(hi));
            wHi[(size_t)m*16384 + h*128 + c] = hi;
            wLo[(size_t)m*16384 + h*128 + c] = lo;
        }
    }
}

// ============ K1: conv -> fuse GEMM -> relu -> hs/hr; 16-row tiles, 256 blocks =
__global__ __launch_bounds__(256) void k_fuse_all(
    const float* __restrict__ data,
    const float* __restrict__ W3, const float* __restrict__ W5,
    const float* __restrict__ W31T,
    const float* __restrict__ Beff1, const float* __restrict__ Beff2,
    const float* __restrict__ b12, const float* __restrict__ b22,
    const float* __restrict__ b31,
    const float* __restrict__ wf, const float* __restrict__ bf,
    const float* __restrict__ w1, const float* __restrict__ b1,
    float* __restrict__ hs, float* __restrict__ hrT, float* __restrict__ XT)
{
    __shared__ __align__(16) float sb[11648];   // 46.6 KB
    float* At   = sb;            // conv out [384][18]; phase2: xT[128][18] @0, Wb @2304
    float* Wt   = sb + 6912;     // [32][128]
    float* dinT = sb + 11008;    // [16][40]
    int blk = blockIdx.x; int row0 = blk*16;
    int b = row0 >> 7; int s0 = row0 & 127;
    int tid = threadIdx.x; int h = tid & 127; int g = tid >> 7;

    for (int idx = tid; idx < 576; idx += 256){
        int r = idx >> 4, d = idx & 15;
        int sp = s0 - 10 + r;
        dinT[d*40 + r] = (sp >= 0 && sp < SS) ? data[(b*SS+sp)*DIN + d] : 0.f;
    }
    __syncthreads();

    // ---- conv: thread = channel h, 8 rows (g*8 .. g*8+7) ----
    float a1[8], a2[8], a3[8];
    #pragma unroll
    for (int m = 0; m < 8; ++m){ a1[m]=0.f; a2[m]=0.f; a3[m]=0.f; }
    for (int d = 0; d < DIN; ++d){
        float w3v[3], w5v[5];
        #pragma unroll
        for (int k = 0; k < 3; ++k) w3v[k] = W3[(k*DIN+d)*HH + h];
        #pragma unroll
        for (int k = 0; k < 5; ++k) w5v[k] = W5[(k*DIN+d)*HH + h];
        float w31v = W31T[d*HH + h];
        const float* dp = dinT + d*40;
        #pragma unroll
        for (int sub = 0; sub < 2; ++sub){
            int rb = g*8 + sub*4;
            const float4* qp = reinterpret_cast<const float4*>(dp + rb);
            float4 q0=qp[0],q1=qp[1],q2=qp[2],q3=qp[3],q4=qp[4],q5=qp[5];
            float qf[24] = {q0.x,q0.y,q0.z,q0.w, q1.x,q1.y,q1.z,q1.w,
                            q2.x,q2.y,q2.z,q2.w, q3.x,q3.y,q3.z,q3.w,
                            q4.x,q4.y,q4.z,q4.w, q5.x,q5.y,q5.z,q5.w};
            #pragma unroll
            for (int tp = 0; tp < 4; ++tp){
                int m = sub*4 + tp;
                #pragma unroll
                for (int k = 0; k < 3; ++k) a1[m] = fmaf(qf[tp+3*k+7], w3v[k], a1[m]);
                #pragma unroll
                for (int k = 0; k < 5; ++k) a2[m] = fmaf(qf[tp+5*k], w5v[k], a2[m]);
                a3[m] = fmaf(qf[tp+10], w31v, a3[m]);
            }
        }
    }
    {
        float be1[3] = {Beff1[h], Beff1[HH+h], Beff1[2*HH+h]};
        float be2[5] = {Beff2[h], Beff2[HH+h], Beff2[2*HH+h], Beff2[3*HH+h], Beff2[4*HH+h]};
        float bv12 = b12[h], bv22 = b22[h], bv31 = b31[h];
        #pragma unroll
        for (int m = 0; m < 8; ++m){
            int rl = g*8 + m;
            int s = s0 + rl;
            float v1 = a1[m] + bv12;
            #pragma unroll
            for (int k = 0; k < 3; ++k)
                if ((unsigned)(s + 3*k - 3) < SS) v1 += be1[k];
            float v2 = a2[m] + bv22;
            #pragma unroll
            for (int k = 0; k < 5; ++k)
                if ((unsigned)(s + 5*k - 10) < SS) v2 += be2[k];
            At[h*18 + rl]        = v1;
            At[(HH+h)*18 + rl]   = v2;
            At[(2*HH+h)*18 + rl] = a3[m] + bv31;
        }
    }
    __syncthreads();

    // ---- fuse GEMM: x = relu(xcat @ wf + bf); 2 rows x 4 cols per thread ----
    int r0 = (tid>>5)*2, c0 = (tid&31)*4;
    float4 facc[2] = {{0,0,0,0},{0,0,0,0}};
    for (int ch = 0; ch < 12; ++ch){
        int kk0 = ch*32;
        #pragma unroll
        for (int u = 0; u < 4; ++u){
            int k = (tid>>5) + 8*u;
            *reinterpret_cast<float4*>(Wt + k*128 + c0) =
                *reinterpret_cast<const float4*>(wf + (size_t)(kk0+k)*128 + c0);
        }
        __syncthreads();
        #pragma unroll 4
        for (int k = 0; k < 32; ++k){
            float2 a = *reinterpret_cast<const float2*>(At + (kk0+k)*18 + r0);
            float4 w = *reinterpret_cast<const float4*>(Wt + k*128 + c0);
            facc[0] = f4fma(a.x, w, facc[0]);
            facc[1] = f4fma(a.y, w, facc[1]);
        }
        __syncthreads();
    }
    float* xT = sb;            // [128][18]
    float* Wb = sb + 2304;
    float* Wa = sb + 6912;     // Wt region
    {
        float4 bf4 = *reinterpret_cast<const float4*>(bf + c0);
        #pragma unroll
        for (int u = 0; u < 2; ++u){
            float4 v = make_float4(fmaxf(facc[u].x+bf4.x,0.f), fmaxf(facc[u].y+bf4.y,0.f),
                                   fmaxf(facc[u].z+bf4.z,0.f), fmaxf(facc[u].w+bf4.w,0.f));
            xT[(c0+0)*18 + r0+u] = v.x;
            xT[(c0+1)*18 + r0+u] = v.y;
            xT[(c0+2)*18 + r0+u] = v.z;
            xT[(c0+3)*18 + r0+u] = v.w;
        }
    }
    __syncthreads();

    // ---- hs/hr GEMMs (K=128) ----
    float4 as[2] = {{0,0,0,0},{0,0,0,0}};
    float4 ar[2] = {{0,0,0,0},{0,0,0,0}};
    for (int ch = 0; ch < 4; ++ch){
        int ck0 = ch*32;
        #pragma unroll
        for (int u = 0; u < 4; ++u){
            int k = (tid>>5) + 8*u;
            *reinterpret_cast<float4*>(Wa + k*128 + c0) =
                *reinterpret_cast<const float4*>(w1 + (size_t)(ck0+k)*128 + c0);
            *reinterpret_cast<float4*>(Wb + k*128 + c0) =
                *reinterpret_cast<const float4*>(w1 + (size_t)(128+ck0+k)*128 + c0);
        }
        __syncthreads();
        #pragma unroll 4
        for (int k = 0; k < 32; ++k){
            float2 a = *reinterpret_cast<const float2*>(xT + (ck0+k)*18 + r0);
            float4 wa = *reinterpret_cast<const float4*>(Wa + k*128 + c0);
            float4 wb = *reinterpret_cast<const float4*>(Wb + k*128 + c0);
            as[0]=f4fma(a.x,wa,as[0]); ar[0]=f4fma(a.x,wb,ar[0]);
            as[1]=f4fma(a.y,wa,as[1]); ar[1]=f4fma(a.y,wb,ar[1]);
        }
        __syncthreads();
    }
    float4 b14 = *reinterpret_cast<const float4*>(b1 + c0);
    int rin = s0 + r0;
    #pragma unroll
    for (int u = 0; u < 2; ++u){
        *reinterpret_cast<float4*>(hs + (size_t)(row0+r0+u)*128 + c0) =
            make_float4(as[u].x, as[u].y, as[u].z, as[u].w);
        hrT[((size_t)b*HH + c0+0)*SS + rin+u] = ar[u].x + b14.x;
        hrT[((size_t)b*HH + c0+1)*SS + rin+u] = ar[u].y + b14.y;
        hrT[((size_t)b*HH + c0+2)*SS + rin+u] = ar[u].z + b14.z;
        hrT[((size_t)b*HH + c0+3)*SS + rin+u] = ar[u].w + b14.w;
    }
    for (int idx = tid; idx < 2048; idx += 256){
        int c = idx >> 4, s = idx & 15;
        XT[((size_t)(b*HH + c))*SS + s0 + s] = xT[c*18 + s];
    }
}

// ============ K2: edge logits + argmax; emits adjT (bf16) + deginv ============
__global__ __launch_bounds__(256) void k_adj(
    const float* __restrict__ hs, const float* __restrict__ hrT,
    const float* __restrict__ w2, const float* __restrict__ b2,
    const float* __restrict__ gu, unsigned short* __restrict__ adjT,
    float* __restrict__ deginv)
{
    int blk = blockIdx.x; int b = blk >> 4; int j0 = (blk & 15) * 8;
    int tid = threadIdx.x; int i = tid & 127; int g = tid >> 7;
    __shared__ float hsL[8][128];
    __shared__ float w20L[128], w21L[128];
    __shared__ int degS[8];
    for (int idx = tid; idx < 1024; idx += 256){
        int jj = idx >> 7, h = idx & 127;
        hsL[jj][h] = hs[(size_t)(b*SS + j0 + jj)*HH + h];
    }
    if (tid < 128){ w20L[tid] = w2[tid*2]; w21L[tid] = w2[tid*2+1]; }
    if (tid < 8) degS[tid] = 0;
    __syncthreads();
    float d0[4] = {0,0,0,0}, d1[4] = {0,0,0,0};
    const float* hrb = hrT + (size_t)b*HH*SS + i;
    #pragma unroll 4
    for (int h = 0; h < 128; ++h){
        float hrv = hrb[(size_t)h*SS];
        float wa = w20L[h], wb = w21L[h];
        float r0 = fmaxf(hsL[g*4+0][h] + hrv, 0.f);
        float r1 = fmaxf(hsL[g*4+1][h] + hrv, 0.f);
        float r2 = fmaxf(hsL[g*4+2][h] + hrv, 0.f);
        float r3 = fmaxf(hsL[g*4+3][h] + hrv, 0.f);
        d0[0]=fmaf(r0,wa,d0[0]); d1[0]=fmaf(r0,wb,d1[0]);
        d0[1]=fmaf(r1,wa,d0[1]); d1[1]=fmaf(r1,wb,d1[1]);
        d0[2]=fmaf(r2,wa,d0[2]); d1[2]=fmaf(r2,wb,d1[2]);
        d0[3]=fmaf(r3,wa,d0[3]); d1[3]=fmaf(r3,wb,d1[3]);
    }
    float b20 = b2[0], b21 = b2[1];
    #pragma unroll
    for (int jj = 0; jj < 4; ++jj){
        int j = j0 + g*4 + jj;
        size_t e = (size_t)(b*SS + i)*SS + j;
        float2 uv = *reinterpret_cast<const float2*>(gu + e*2);
        float u0 = fminf(fmaxf(uv.x, 1e-6f), 0.999999f);
        float u1 = fminf(fmaxf(uv.y, 1e-6f), 0.999999f);
        float g0 = -logf(-logf(u0));
        float g1 = -logf(-logf(u1));
        float y0 = d0[jj] + b20 + g0;
        float y1 = d1[jj] + b21 + g1;
        bool av = (j > i) && (y0 >= y1);
        adjT[(size_t)(b*SS + j)*SS + i] = av ? (unsigned short)0x3F80 : (unsigned short)0;
        unsigned long long msk = __ballot(av);
        if ((tid & 63) == 0) atomicAdd(&degS[g*4+jj], (int)__popcll(msk));
    }
    __syncthreads();
    if (tid < 8) deginv[b*SS + j0 + tid] = 1.f / fmaxf((float)degS[tid], 1.f);
}

// ============ K3: cooperative — all 3 GNN layers + head in one launch =========
// grid 128 = (b, j-quarter); adjT staged once; grid.sync between layers.
#define AGGH 0
#define AGGL 4352
#define ADJA 8704      // persists across layers
#define XNJH 13056
#define XNJL 17408
#define XH   21760
#define XL   30976
#define LINA 21760     // aliases XH/XL (dead after agg each layer)
__global__ __launch_bounds__(256) void k_gnn3(
    const unsigned short* __restrict__ adjT,
    const float* __restrict__ XT, float* __restrict__ T0,
    float* __restrict__ T1, float* __restrict__ T2,
    const float* __restrict__ deginv,
    const float* __restrict__ gamma, const float* __restrict__ beta,
    float* __restrict__ accf,
    const unsigned short* __restrict__ wHi, const unsigned short* __restrict__ wLo,
    const float* __restrict__ bl,
    const float* __restrict__ wg, const float* __restrict__ bg,
    const float* __restrict__ we, const float* __restrict__ be,
    const float* __restrict__ wo, const float* __restrict__ bo,
    float* __restrict__ out)
{
    cooperative_groups::grid_group grid = cooperative_groups::this_grid();
    __shared__ __align__(16) unsigned short pool[42240];   // 84.5 KB
    __shared__ float2 scsh[128];
    __shared__ float dinvL[32];
    __shared__ float2 redS[128];
    __shared__ float blL[128];
    int blk = blockIdx.x; int b = blk >> 2; int j0 = (blk & 3) * 32;
    int tid = threadIdx.x; int lane = tid & 63; int w = tid >> 6;
    int frow = lane & 15, fk = (lane >> 4) * 8;

    if (tid < 32) dinvL[tid] = deginv[b*SS + j0 + tid];
    for (int task = tid; task < 512; task += 256){
        int jl = task >> 4, c8 = task & 15;
        *reinterpret_cast<uint4*>(pool + ADJA + jl*136 + c8*8) =
            *reinterpret_cast<const uint4*>(adjT + ((size_t)(b*SS + j0 + jl))*SS + c8*8);
    }

    const float* xnTs[3] = {XT, T0, T1};
    float*       outTs[3] = {T0, T1, T2};

    for (int l = 0; l < 3; ++l){
        const float* xnT = xnTs[l];
        float* outT = outTs[l];
        const unsigned short* wptr[4] = {wHi + (size_t)l*16384, wLo + (size_t)l*16384,
                                         wHi + (size_t)(3+l)*16384, wLo + (size_t)(3+l)*16384};
        if (tid < 128){
            if (l > 0){
                float2 s = reinterpret_cast<const float2*>(accf + (size_t)(l-1)*256)[tid];
                float m = s.x * (1.f/4096.f);
                float var = fmaxf(s.y * (1.f/4096.f) - m*m, 0.f);
                float sc = gamma[(l-1)*128+tid] / sqrtf(var + 1e-5f);
                scsh[tid] = make_float2(sc, beta[(l-1)*128+tid] - m*sc);
            } else scsh[tid] = make_float2(1.f, 0.f);
            redS[tid] = make_float2(0.f, 0.f);
            blL[tid] = bl[l*128 + tid];
        }
        __syncthreads();

        // ---- agg: C[m=j 32][n=h 128] = adjT x xn_eff, K=i in 2 chunks of 64 --
        int mt = w & 1, ntb = (w >> 1) * 4;
        vf4 acc[4]; acc[0]=0.f; acc[1]=0.f; acc[2]=0.f; acc[3]=0.f;
        for (int cs = 0; cs < 2; ++cs){
            for (int task = tid; task < 2048; task += 256){
                int hh = task >> 4, q = task & 15;
                float4 v = *reinterpret_cast<const float4*>(
                    xnT + ((size_t)(b*HH + hh))*SS + cs*64 + q*4);
                float2 ss = scsh[hh];
                float e0 = fmaf(v.x, ss.x, ss.y), e1 = fmaf(v.y, ss.x, ss.y);
                float e2 = fmaf(v.z, ss.x, ss.y), e3 = fmaf(v.w, ss.x, ss.y);
                unsigned short h0 = f2bf(e0), h1 = f2bf(e1), h2 = f2bf(e2), h3 = f2bf(e3);
                unsigned int hA = (unsigned int)h0 | ((unsigned int)h1 << 16);
                unsigned int hB = (unsigned int)h2 | ((unsigned int)h3 << 16);
                unsigned short l0 = f2bf(e0 - bf2f(h0)), l1 = f2bf(e1 - bf2f(h1));
                unsigned short l2 = f2bf(e2 - bf2f(h2)), l3 = f2bf(e3 - bf2f(h3));
                unsigned int lA = (unsigned int)l0 | ((unsigned int)l1 << 16);
                unsigned int lB = (unsigned int)l2 | ((unsigned int)l3 << 16);
                *reinterpret_cast<uint2*>(pool + XH + hh*72 + q*4) = make_uint2(hA, hB);
                *reinterpret_cast<uint2*>(pool + XL + hh*72 + q*4) = make_uint2(lA, lB);
            }
            __syncthreads();
            #pragma unroll
            for (int ks = 0; ks < 2; ++ks){
                short8 af = *reinterpret_cast<const short8*>(
                    pool + ADJA + (mt*16 + frow)*136 + cs*64 + ks*32 + fk);
                #pragma unroll
                for (int ntl = 0; ntl < 4; ++ntl){
                    int nt = ntb + ntl;
                    short8 bh = *reinterpret_cast<const short8*>(
                        pool + XH + (nt*16 + frow)*72 + ks*32 + fk);
                    short8 bo = *reinterpret_cast<const short8*>(
                        pool + XL + (nt*16 + frow)*72 + ks*32 + fk);
                    acc[ntl] = __builtin_amdgcn_mfma_f32_16x16x32_bf16(af, bh, acc[ntl], 0, 0, 0);
                    acc[ntl] = __builtin_amdgcn_mfma_f32_16x16x32_bf16(af, bo, acc[ntl], 0, 0, 0);
                }
            }
            __syncthreads();
        }
        // agg epilogue -> AGGH/AGGL [j][c=h]; stage xnJ [j][c] hi/lo
        #pragma unroll
        for (int ntl = 0; ntl < 4; ++ntl){
            int hh = (ntb + ntl)*16 + frow;
            #pragma unroll
            for (int r = 0; r < 4; ++r){
                int jl = mt*16 + (lane>>4)*4 + r;
                float v = acc[ntl][r] * dinvL[jl];
                unsigned short hi = f2bf(v);
                pool[AGGH + jl*136 + hh] = hi;
                pool[AGGL + jl*136 + hh] = f2bf(v - bf2f(hi));
            }
        }
        {
            int jg = tid >> 5, cg = tid & 31;
            float mv[4][4];
            #pragma unroll
            for (int e = 0; e < 4; ++e){
                float4 v = *reinterpret_cast<const float4*>(
                    xnT + ((size_t)(b*HH + cg*4 + e))*SS + j0 + jg*4);
                float2 ss = scsh[cg*4 + e];
                mv[e][0]=fmaf(v.x,ss.x,ss.y); mv[e][1]=fmaf(v.y,ss.x,ss.y);
                mv[e][2]=fmaf(v.z,ss.x,ss.y); mv[e][3]=fmaf(v.w,ss.x,ss.y);
            }
            #pragma unroll
            for (int f = 0; f < 4; ++f){
                int jl = jg*4 + f;
                unsigned short h0=f2bf(mv[0][f]), h1=f2bf(mv[1][f]), h2=f2bf(mv[2][f]), h3=f2bf(mv[3][f]);
                unsigned int a0 = (unsigned int)h0 | ((unsigned int)h1<<16);
                unsigned int a1v = (unsigned int)h2 | ((unsigned int)h3<<16);
                unsigned short l0=f2bf(mv[0][f]-bf2f(h0)), l1=f2bf(mv[1][f]-bf2f(h1));
                unsigned short l2=f2bf(mv[2][f]-bf2f(h2)), l3=f2bf(mv[3][f]-bf2f(h3));
                unsigned int b0 = (unsigned int)l0 | ((unsigned int)l1<<16);
                unsigned int b1v = (unsigned int)l2 | ((unsigned int)l3<<16);
                *reinterpret_cast<uint2*>(pool + XNJH + jl*136 + cg*4) = make_uint2(a0, a1v);
                *reinterpret_cast<uint2*>(pool + XNJL + jl*136 + cg*4) = make_uint2(b0, b1v);
            }
        }
        __syncthreads();

        // ---- lin: C[m=h 128][n=j 32] = wlT x agg + wrT x xnJ, K=128 ----------
        vf4 lacc[2][2];
        lacc[0][0]=0.f; lacc[0][1]=0.f; lacc[1][0]=0.f; lacc[1][1]=0.f;
        for (int ck = 0; ck < 4; ++ck){
            for (int task = tid; task < 2048; task += 256){
                int mat = task >> 9, hh = (task >> 2) & 127, q = task & 3;
                *reinterpret_cast<uint4*>(pool + LINA + mat*5120 + hh*40 + q*8) =
                    *reinterpret_cast<const uint4*>(wptr[mat] + (size_t)hh*128 + ck*32 + q*8);
            }
            __syncthreads();
            #pragma unroll
            for (int mat = 0; mat < 2; ++mat){
                int Ah = LINA + (mat*2)*5120;
                int Al = LINA + (mat*2+1)*5120;
                int Bh = mat ? XNJH : AGGH;
                int Bl = mat ? XNJL : AGGL;
                #pragma unroll
                for (int mi = 0; mi < 2; ++mi){
                    int mt2 = 2*w + mi;
                    short8 ah = *reinterpret_cast<const short8*>(pool + Ah + (mt2*16 + frow)*40 + fk);
                    short8 al = *reinterpret_cast<const short8*>(pool + Al + (mt2*16 + frow)*40 + fk);
                    #pragma unroll
                    for (int ntl = 0; ntl < 2; ++ntl){
                        short8 bh = *reinterpret_cast<const short8*>(
                            pool + Bh + (ntl*16 + frow)*136 + ck*32 + fk);
                        short8 bo = *reinterpret_cast<const short8*>(
                            pool + Bl + (ntl*16 + frow)*136 + ck*32 + fk);
                        lacc[mi][ntl] = __builtin_amdgcn_mfma_f32_16x16x32_bf16(ah, bh, lacc[mi][ntl], 0,0,0);
                        lacc[mi][ntl] = __builtin_amdgcn_mfma_f32_16x16x32_bf16(ah, bo, lacc[mi][ntl], 0,0,0);
                        lacc[mi][ntl] = __builtin_amdgcn_mfma_f32_16x16x32_bf16(al, bh, lacc[mi][ntl], 0,0,0);
                    }
                }
            }
            __syncthreads();
        }
        // epilogue: bias, store, BN partials via 16-lane shfl reduce (wave-disjoint hh)
        #pragma unroll
        for (int mi = 0; mi < 2; ++mi){
            #pragma unroll
            for (int ntl = 0; ntl < 2; ++ntl){
                #pragma unroll
                for (int r = 0; r < 4; ++r){
                    int hh = (2*w + mi)*16 + (lane>>4)*4 + r;
                    int jl = ntl*16 + (lane & 15);
                    float v = lacc[mi][ntl][r] + blL[hh];
                    outT[((size_t)(b*HH + hh))*SS + j0 + jl] = v;
                    float s1 = v, s2 = v*v;
                    #pragma unroll
                    for (int off = 1; off < 16; off <<= 1){
                        s1 += __shfl_xor(s1, off, 64);
                        s2 += __shfl_xor(s2, off, 64);
                    }
                    if ((lane & 15) == 0){ redS[hh].x += s1; redS[hh].y += s2; }
                }
            }
        }
        __syncthreads();
        if (tid < 128){
            atomicAdd(&accf[(size_t)l*256 + 2*tid],   redS[tid].x);
            atomicAdd(&accf[(size_t)l*256 + 2*tid+1], redS[tid].y);
        }
        __threadfence();
        grid.sync();
    }

    // ---- head: blocks 0..31 ----
    if (blk < BB){
        float* xw = reinterpret_cast<float*>(pool);
        int bb = blk; int t = tid;
        const float* outs3[3] = {T0, T1, T2};
        if (t < 128){
            float a = bg[0];
            #pragma unroll
            for (int l = 0; l < 3; ++l){
                float2 s = reinterpret_cast<const float2*>(accf + (size_t)l*256)[t];
                float m = s.x * (1.f/4096.f);
                float var = fmaxf(s.y * (1.f/4096.f) - m*m, 0.f);
                float sc = gamma[l*128+t] / sqrtf(var + 1e-5f);
                float sh = beta[l*128+t] - m*sc;
                float val = fmaf(outs3[l][((size_t)(bb*HH + t))*SS + SS-1], sc, sh);
                a = fmaf(val, wg[l], a);
            }
            xw[t] = fmaxf(a, 0.f);
        }
        __syncthreads();
        if (t < 64){
            float acc = be[t];
            for (int h = 0; h < HH; ++h) acc = fmaf(xw[h], we[h*64 + t], acc);
            float h2 = fmaxf(acc, 0.f);
            float r = h2 * wo[t];
            #pragma unroll
            for (int off = 32; off; off >>= 1) r += __shfl_down(r, off, 64);
            if (t == 0) out[bb] = r + bo[0];
        }
    }
}

// ==============================================================================
extern "C" void kernel_launch(void* const* d_in, const int* in_sizes, int n_in,
                              void* d_out, int out_size, void* d_ws, size_t ws_size,
                              hipStream_t stream)
{
    const float* data = (const float*)d_in[0];
    const float* gu   = (const float*)d_in[1];
    const float* w11  = (const float*)d_in[2];
    const float* b11  = (const float*)d_in[3];
    const float* w12  = (const float*)d_in[4];
    const float* b12  = (const float*)d_in[5];
    const float* w21  = (const float*)d_in[6];
    const float* b21  = (const float*)d_in[7];
    const float* w22  = (const float*)d_in[8];
    const float* b22  = (const float*)d_in[9];
    const float* w31  = (const float*)d_in[10];
    const float* b31  = (const float*)d_in[11];
    const float* wf   = (const float*)d_in[12];
    const float* bf   = (const float*)d_in[13];
    const float* w1   = (const float*)d_in[14];
    const float* b1   = (const float*)d_in[15];
    const float* w2   = (const float*)d_in[16];
    const float* b2   = (const float*)d_in[17];
    const float* wl   = (const float*)d_in[18];
    const float* bl   = (const float*)d_in[19];
    const float* wr   = (const float*)d_in[20];
    const float* gamma= (const float*)d_in[21];
    const float* beta = (const float*)d_in[22];
    const float* wg   = (const float*)d_in[23];
    const float* bg   = (const float*)d_in[24];
    const float* we   = (const float*)d_in[25];
    const float* be   = (const float*)d_in[26];
    const float* wo   = (const float*)d_in[27];
    const float* bo   = (const float*)d_in[28];
    float* out = (float*)d_out;

    float* ws = (float*)d_ws;
    float* hs   = ws;                          // NBSH
    float* hrT  = ws + (size_t)NBSH;
    float* XT   = ws + (size_t)2*NBSH;
    float* T0   = ws + (size_t)3*NBSH;
    float* T1   = ws + (size_t)4*NBSH;
    float* T2   = ws + (size_t)5*NBSH;
    float* G    = ws + (size_t)6*NBSH;
    float* W3    = G;                          // 6144
    float* W5    = G + 6144;                   // 10240
    float* W31T  = G + 16384;                  // 2048
    float* Beff1 = G + 18432;                  // 384
    float* Beff2 = G + 18816;                  // 640
    float* accf  = G + 19456;                  // 768
    float* dinv  = G + 20224;                  // 4096
    unsigned short* adjTG = (unsigned short*)(G + 24320);           // 524288 us
    unsigned short* wHi   = (unsigned short*)(G + 24320 + 262144);  // 98304 us
    unsigned short* wLo   = (unsigned short*)(G + 24320 + 262144 + 49152);

    k_prep<<<40, 256, 0, stream>>>(w12, w22, w31, w11, b11, w21, b21, wl, wr,
                                   W3, W5, W31T, Beff1, Beff2, accf, wHi, wLo);
    k_fuse_all<<<256, 256, 0, stream>>>(data, W3, W5, W31T, Beff1, Beff2,
                                        b12, b22, b31, wf, bf, w1, b1,
                                        hs, hrT, XT);
    k_adj<<<512, 256, 0, stream>>>(hs, hrT, w2, b2, gu, adjTG, dinv);

    const unsigned short* a_adj = adjTG;
    const float* a_XT = XT;
    float* a_T0 = T0; float* a_T1 = T1; float* a_T2 = T2;
    const float* a_dinv = dinv;
    const float* a_gamma = gamma; const float* a_beta = beta;
    float* a_accf = accf;
    const unsigned short* a_wHi = wHi; const unsigned short* a_wLo = wLo;
    const float* a_bl = bl;
    const float* a_wg = wg; const float* a_bg = bg;
    const float* a_we = we; const float* a_be = be;
    const float* a_wo = wo; const float* a_bo = bo;
    float* a_out = out;
    void* args[] = {
        (void*)&a_adj, (void*)&a_XT, (void*)&a_T0, (void*)&a_T1, (void*)&a_T2,
        (void*)&a_dinv, (void*)&a_gamma, (void*)&a_beta, (void*)&a_accf,
        (void*)&a_wHi, (void*)&a_wLo, (void*)&a_bl,
        (void*)&a_wg, (void*)&a_bg, (void*)&a_we, (void*)&a_be,
        (void*)&a_wo, (void*)&a_bo, (void*)&a_out
    };
    hipLaunchCooperativeKernel((void*)k_gnn3, dim3(128), dim3(256), args, 0, stream);
}

// Round 12
// 141.883 us; speedup vs baseline: 1.7037x; 1.7037x over previous
//
#include <hip/hip_runtime.h>
#include <math.h>

#define BB 32
#define SS 128
#define DIN 16
#define HH 128
#define NBSH (BB*SS*HH)   // 524288

typedef __attribute__((ext_vector_type(8))) short short8;
typedef __attribute__((ext_vector_type(4))) float vf4;

__device__ __forceinline__ float4 f4fma(float s, float4 w, float4 c){
    return make_float4(fmaf(s,w.x,c.x), fmaf(s,w.y,c.y), fmaf(s,w.z,c.z), fmaf(s,w.w,c.w));
}
__device__ __forceinline__ unsigned short f2bf(float x){
    union { float f; unsigned int u; } v; v.f = x;
    unsigned int r = v.u + 0x7FFF + ((v.u >> 16) & 1);
    return (unsigned short)(r >> 16);
}
__device__ __forceinline__ float bf2f(unsigned short b){
    union { unsigned int u; float f; } v; v.u = ((unsigned int)b) << 16;
    return v.f;
}

// ============ K0: prep — composite conv weights + wl/wr transposed bf16 splits =
__global__ __launch_bounds__(256) void k_prep(
    const float* __restrict__ w12, const float* __restrict__ w22,
    const float* __restrict__ w31,
    const float* __restrict__ w11, const float* __restrict__ b11,
    const float* __restrict__ w21, const float* __restrict__ b21,
    const float* __restrict__ wl, const float* __restrict__ wr,
    float* __restrict__ W3, float* __restrict__ W5, float* __restrict__ W31T,
    float* __restrict__ Beff1, float* __restrict__ Beff2, float* __restrict__ accf,
    unsigned short* __restrict__ wHi, unsigned short* __restrict__ wLo)
{
    __shared__ float W12L[8*384];
    __shared__ float W22L[8*640];
    __shared__ float w11L[2048], w21L[2048], b11L[128], b21L[128];
    int blk = blockIdx.x; int tid = threadIdx.x;

    if (blk < 16){
        int h0 = blk*8;
        for (int i = tid; i < 768; i += 256){
            int hl = i/96, o4 = i%96;
            *reinterpret_cast<float4*>(W12L + hl*384 + o4*4) =
                reinterpret_cast<const float4*>(w12)[(h0+hl)*96 + o4];
        }
        for (int i = tid; i < 1280; i += 256){
            int hl = i/160, o4 = i%160;
            *reinterpret_cast<float4*>(W22L + hl*640 + o4*4) =
                reinterpret_cast<const float4*>(w22)[(h0+hl)*160 + o4];
        }
        for (int i = tid; i < 512; i += 256)
            *reinterpret_cast<float4*>(w11L + i*4) = reinterpret_cast<const float4*>(w11)[i];
        for (int i = tid; i < 512; i += 256)
            *reinterpret_cast<float4*>(w21L + i*4) = reinterpret_cast<const float4*>(w21)[i];
        if (tid < 128){ b11L[tid] = b11[tid]; b21L[tid] = b21[tid]; }
        if (blk == 0){ for (int i = tid; i < 768; i += 256) accf[i] = 0.f; }
        __syncthreads();

        for (int T = tid; T < 1216; T += 256){
            if (T < 384){
                int hl = T/48, kd = T%48, k = kd>>4, d = kd&15;
                float a = 0.f;
                #pragma unroll 4
                for (int c = 0; c < HH; ++c) a = fmaf(W12L[hl*384 + c*3 + k], w11L[c*16 + d], a);
                W3[(k*16+d)*128 + h0+hl] = a;
            } else if (T < 1024){
                int tt = T-384, hl = tt/80, kd = tt%80, k = kd>>4, d = kd&15;
                float a = 0.f;
                #pragma unroll 4
                for (int c = 0; c < HH; ++c) a = fmaf(W22L[hl*640 + c*5 + k], w21L[c*16 + d], a);
                W5[(k*16+d)*128 + h0+hl] = a;
            } else if (T < 1048){
                int tt = T-1024, hl = tt/3, k = tt%3;
                float a = 0.f;
                #pragma unroll 4
                for (int c = 0; c < HH; ++c) a = fmaf(W12L[hl*384 + c*3 + k], b11L[c], a);
                Beff1[k*128 + h0+hl] = a;
            } else if (T < 1088){
                int tt = T-1048, hl = tt/5, k = tt%5;
                float a = 0.f;
                #pragma unroll 4
                for (int c = 0; c < HH; ++c) a = fmaf(W22L[hl*640 + c*5 + k], b21L[c], a);
                Beff2[k*128 + h0+hl] = a;
            } else {
                int tt = T-1088, hl = tt>>4, d = tt&15;
                W31T[d*128 + h0+hl] = w31[(h0+hl)*16 + d];
            }
        }
    } else {
        int q = blk - 16;          // 0..23
        int h = tid & 127; int half = tid >> 7;
        for (int rl = half; rl < 32; rl += 2){
            int r = q*32 + rl;     // 0..767
            int m = r >> 7;
            int c = r & 127;
            const float* src = (m < 3) ? (wl + (size_t)m*16384) : (wr + (size_t)(m-3)*16384);
            float v = src[c*128 + h];
            unsigned short hi = f2bf(v);
            unsigned short lo = f2bf(v - bf2f(hi));
            wHi[(size_t)m*16384 + h*128 + c] = hi;
            wLo[(size_t)m*16384 + h*128 + c] = lo;
        }
    }
}

// ============ K1: conv -> fuse GEMM -> relu -> hs/hr; 16-row tiles, 256 blocks =
__global__ __launch_bounds__(256) void k_fuse_all(
    const float* __restrict__ data,
    const float* __restrict__ W3, const float* __restrict__ W5,
    const float* __restrict__ W31T,
    const float* __restrict__ Beff1, const float* __restrict__ Beff2,
    const float* __restrict__ b12, const float* __restrict__ b22,
    const float* __restrict__ b31,
    const float* __restrict__ wf, const float* __restrict__ bf,
    const float* __restrict__ w1, const float* __restrict__ b1,
    float* __restrict__ hs, float* __restrict__ hrT, float* __restrict__ XT)
{
    __shared__ __align__(16) float sb[11648];   // 46.6 KB
    float* At   = sb;            // conv out [384][18]; phase2: xT[128][18] @0, Wb @2304
    float* Wt   = sb + 6912;     // [32][128]
    float* dinT = sb + 11008;    // [16][40]
    int blk = blockIdx.x; int row0 = blk*16;
    int b = row0 >> 7; int s0 = row0 & 127;
    int tid = threadIdx.x; int h = tid & 127; int g = tid >> 7;

    for (int idx = tid; idx < 576; idx += 256){
        int r = idx >> 4, d = idx & 15;
        int sp = s0 - 10 + r;
        dinT[d*40 + r] = (sp >= 0 && sp < SS) ? data[(b*SS+sp)*DIN + d] : 0.f;
    }
    __syncthreads();

    float a1[8], a2[8], a3[8];
    #pragma unroll
    for (int m = 0; m < 8; ++m){ a1[m]=0.f; a2[m]=0.f; a3[m]=0.f; }
    for (int d = 0; d < DIN; ++d){
        float w3v[3], w5v[5];
        #pragma unroll
        for (int k = 0; k < 3; ++k) w3v[k] = W3[(k*DIN+d)*HH + h];
        #pragma unroll
        for (int k = 0; k < 5; ++k) w5v[k] = W5[(k*DIN+d)*HH + h];
        float w31v = W31T[d*HH + h];
        const float* dp = dinT + d*40;
        #pragma unroll
        for (int sub = 0; sub < 2; ++sub){
            int rb = g*8 + sub*4;
            const float4* qp = reinterpret_cast<const float4*>(dp + rb);
            float4 q0=qp[0],q1=qp[1],q2=qp[2],q3=qp[3],q4=qp[4],q5=qp[5];
            float qf[24] = {q0.x,q0.y,q0.z,q0.w, q1.x,q1.y,q1.z,q1.w,
                            q2.x,q2.y,q2.z,q2.w, q3.x,q3.y,q3.z,q3.w,
                            q4.x,q4.y,q4.z,q4.w, q5.x,q5.y,q5.z,q5.w};
            #pragma unroll
            for (int tp = 0; tp < 4; ++tp){
                int m = sub*4 + tp;
                #pragma unroll
                for (int k = 0; k < 3; ++k) a1[m] = fmaf(qf[tp+3*k+7], w3v[k], a1[m]);
                #pragma unroll
                for (int k = 0; k < 5; ++k) a2[m] = fmaf(qf[tp+5*k], w5v[k], a2[m]);
                a3[m] = fmaf(qf[tp+10], w31v, a3[m]);
            }
        }
    }
    {
        float be1[3] = {Beff1[h], Beff1[HH+h], Beff1[2*HH+h]};
        float be2[5] = {Beff2[h], Beff2[HH+h], Beff2[2*HH+h], Beff2[3*HH+h], Beff2[4*HH+h]};
        float bv12 = b12[h], bv22 = b22[h], bv31 = b31[h];
        #pragma unroll
        for (int m = 0; m < 8; ++m){
            int rl = g*8 + m;
            int s = s0 + rl;
            float v1 = a1[m] + bv12;
            #pragma unroll
            for (int k = 0; k < 3; ++k)
                if ((unsigned)(s + 3*k - 3) < SS) v1 += be1[k];
            float v2 = a2[m] + bv22;
            #pragma unroll
            for (int k = 0; k < 5; ++k)
                if ((unsigned)(s + 5*k - 10) < SS) v2 += be2[k];
            At[h*18 + rl]        = v1;
            At[(HH+h)*18 + rl]   = v2;
            At[(2*HH+h)*18 + rl] = a3[m] + bv31;
        }
    }
    __syncthreads();

    int r0 = (tid>>5)*2, c0 = (tid&31)*4;
    float4 facc[2] = {{0,0,0,0},{0,0,0,0}};
    for (int ch = 0; ch < 12; ++ch){
        int kk0 = ch*32;
        #pragma unroll
        for (int u = 0; u < 4; ++u){
            int k = (tid>>5) + 8*u;
            *reinterpret_cast<float4*>(Wt + k*128 + c0) =
                *reinterpret_cast<const float4*>(wf + (size_t)(kk0+k)*128 + c0);
        }
        __syncthreads();
        #pragma unroll 4
        for (int k = 0; k < 32; ++k){
            float2 a = *reinterpret_cast<const float2*>(At + (kk0+k)*18 + r0);
            float4 w = *reinterpret_cast<const float4*>(Wt + k*128 + c0);
            facc[0] = f4fma(a.x, w, facc[0]);
            facc[1] = f4fma(a.y, w, facc[1]);
        }
        __syncthreads();
    }
    float* xT = sb;            // [128][18]
    float* Wb = sb + 2304;
    float* Wa = sb + 6912;
    {
        float4 bf4 = *reinterpret_cast<const float4*>(bf + c0);
        #pragma unroll
        for (int u = 0; u < 2; ++u){
            float4 v = make_float4(fmaxf(facc[u].x+bf4.x,0.f), fmaxf(facc[u].y+bf4.y,0.f),
                                   fmaxf(facc[u].z+bf4.z,0.f), fmaxf(facc[u].w+bf4.w,0.f));
            xT[(c0+0)*18 + r0+u] = v.x;
            xT[(c0+1)*18 + r0+u] = v.y;
            xT[(c0+2)*18 + r0+u] = v.z;
            xT[(c0+3)*18 + r0+u] = v.w;
        }
    }
    __syncthreads();

    float4 as[2] = {{0,0,0,0},{0,0,0,0}};
    float4 ar[2] = {{0,0,0,0},{0,0,0,0}};
    for (int ch = 0; ch < 4; ++ch){
        int ck0 = ch*32;
        #pragma unroll
        for (int u = 0; u < 4; ++u){
            int k = (tid>>5) + 8*u;
            *reinterpret_cast<float4*>(Wa + k*128 + c0) =
                *reinterpret_cast<const float4*>(w1 + (size_t)(ck0+k)*128 + c0);
            *reinterpret_cast<float4*>(Wb + k*128 + c0) =
                *reinterpret_cast<const float4*>(w1 + (size_t)(128+ck0+k)*128 + c0);
        }
        __syncthreads();
        #pragma unroll 4
        for (int k = 0; k < 32; ++k){
            float2 a = *reinterpret_cast<const float2*>(xT + (ck0+k)*18 + r0);
            float4 wa = *reinterpret_cast<const float4*>(Wa + k*128 + c0);
            float4 wb = *reinterpret_cast<const float4*>(Wb + k*128 + c0);
            as[0]=f4fma(a.x,wa,as[0]); ar[0]=f4fma(a.x,wb,ar[0]);
            as[1]=f4fma(a.y,wa,as[1]); ar[1]=f4fma(a.y,wb,ar[1]);
        }
        __syncthreads();
    }
    float4 b14 = *reinterpret_cast<const float4*>(b1 + c0);
    int rin = s0 + r0;
    #pragma unroll
    for (int u = 0; u < 2; ++u){
        *reinterpret_cast<float4*>(hs + (size_t)(row0+r0+u)*128 + c0) =
            make_float4(as[u].x, as[u].y, as[u].z, as[u].w);
        hrT[((size_t)b*HH + c0+0)*SS + rin+u] = ar[u].x + b14.x;
        hrT[((size_t)b*HH + c0+1)*SS + rin+u] = ar[u].y + b14.y;
        hrT[((size_t)b*HH + c0+2)*SS + rin+u] = ar[u].z + b14.z;
        hrT[((size_t)b*HH + c0+3)*SS + rin+u] = ar[u].w + b14.w;
    }
    for (int idx = tid; idx < 2048; idx += 256){
        int c = idx >> 4, s = idx & 15;
        XT[((size_t)(b*HH + c))*SS + s0 + s] = xT[c*18 + s];
    }
}

// ============ K2: edge logits + argmax; emits adjT (bf16) + deginv ============
__global__ __launch_bounds__(256) void k_adj(
    const float* __restrict__ hs, const float* __restrict__ hrT,
    const float* __restrict__ w2, const float* __restrict__ b2,
    const float* __restrict__ gu, unsigned short* __restrict__ adjT,
    float* __restrict__ deginv)
{
    int blk = blockIdx.x; int b = blk >> 4; int j0 = (blk & 15) * 8;
    int tid = threadIdx.x; int i = tid & 127; int g = tid >> 7;
    __shared__ float hsL[8][128];
    __shared__ float w20L[128], w21L[128];
    __shared__ int degS[8];
    for (int idx = tid; idx < 1024; idx += 256){
        int jj = idx >> 7, h = idx & 127;
        hsL[jj][h] = hs[(size_t)(b*SS + j0 + jj)*HH + h];
    }
    if (tid < 128){ w20L[tid] = w2[tid*2]; w21L[tid] = w2[tid*2+1]; }
    if (tid < 8) degS[tid] = 0;
    __syncthreads();
    float d0[4] = {0,0,0,0}, d1[4] = {0,0,0,0};
    const float* hrb = hrT + (size_t)b*HH*SS + i;
    #pragma unroll 4
    for (int h = 0; h < 128; ++h){
        float hrv = hrb[(size_t)h*SS];
        float wa = w20L[h], wb = w21L[h];
        float r0 = fmaxf(hsL[g*4+0][h] + hrv, 0.f);
        float r1 = fmaxf(hsL[g*4+1][h] + hrv, 0.f);
        float r2 = fmaxf(hsL[g*4+2][h] + hrv, 0.f);
        float r3 = fmaxf(hsL[g*4+3][h] + hrv, 0.f);
        d0[0]=fmaf(r0,wa,d0[0]); d1[0]=fmaf(r0,wb,d1[0]);
        d0[1]=fmaf(r1,wa,d0[1]); d1[1]=fmaf(r1,wb,d1[1]);
        d0[2]=fmaf(r2,wa,d0[2]); d1[2]=fmaf(r2,wb,d1[2]);
        d0[3]=fmaf(r3,wa,d0[3]); d1[3]=fmaf(r3,wb,d1[3]);
    }
    float b20 = b2[0], b21 = b2[1];
    #pragma unroll
    for (int jj = 0; jj < 4; ++jj){
        int j = j0 + g*4 + jj;
        size_t e = (size_t)(b*SS + i)*SS + j;
        float2 uv = *reinterpret_cast<const float2*>(gu + e*2);
        float u0 = fminf(fmaxf(uv.x, 1e-6f), 0.999999f);
        float u1 = fminf(fmaxf(uv.y, 1e-6f), 0.999999f);
        float g0 = -logf(-logf(u0));
        float g1 = -logf(-logf(u1));
        float y0 = d0[jj] + b20 + g0;
        float y1 = d1[jj] + b21 + g1;
        bool av = (j > i) && (y0 >= y1);
        adjT[(size_t)(b*SS + j)*SS + i] = av ? (unsigned short)0x3F80 : (unsigned short)0;
        unsigned long long msk = __ballot(av);
        if ((tid & 63) == 0) atomicAdd(&degS[g*4+jj], (int)__popcll(msk));
    }
    __syncthreads();
    if (tid < 8) deginv[b*SS + j0 + tid] = 1.f / fmaxf((float)degS[tid], 1.f);
}

// ============ K3: MFMA GNN block, 512 threads (8 waves) =======================
// grid 128 = (b, j-quarter). agg: 2x8 tiles / 8 waves = 2 each; lin: 8x2 / 8 = 2.
#define AGGH 0
#define AGGL 4352
#define ADJA 8704
#define XH   13056
#define XL   22272
#define LINA 8704      // aliases ADJA (dead after agg)
#define XNJH 29184
#define XNJL 33536
__global__ __launch_bounds__(512) void k_gnn(
    const unsigned short* __restrict__ adjT, const float* __restrict__ xnT,
    const float* __restrict__ deginv,
    const float* __restrict__ gammaP, const float* __restrict__ betaP,
    const float* __restrict__ accP, int aff,
    const unsigned short* __restrict__ wlH, const unsigned short* __restrict__ wlL,
    const unsigned short* __restrict__ wrH, const unsigned short* __restrict__ wrL,
    const float* __restrict__ bl,
    float* __restrict__ outT, float* __restrict__ accL)
{
    __shared__ __align__(16) unsigned short pool[37888];
    __shared__ float2 scsh[128];
    __shared__ float dinvL[32];
    __shared__ float2 redS[128];
    __shared__ float blL[128];
    int blk = blockIdx.x; int b = blk >> 2; int j0 = (blk & 3) * 32;
    int tid = threadIdx.x; int lane = tid & 63; int w = tid >> 6;   // w in [0,8)
    int frow = lane & 15, fk = (lane >> 4) * 8;

    if (tid < 128){
        if (aff){
            float2 s = reinterpret_cast<const float2*>(accP)[tid];
            float m = s.x * (1.f/4096.f);
            float var = fmaxf(s.y * (1.f/4096.f) - m*m, 0.f);
            float sc = gammaP[tid] / sqrtf(var + 1e-5f);
            scsh[tid] = make_float2(sc, betaP[tid] - m*sc);
        } else scsh[tid] = make_float2(1.f, 0.f);
        redS[tid] = make_float2(0.f, 0.f);
        blL[tid] = bl[tid];
    }
    if (tid < 32) dinvL[tid] = deginv[b*SS + j0 + tid];
    __syncthreads();   // fence before any scsh read (round-9 lesson)

    // stage adjT rows j0..j0+31 (bf16, stride 136): 512 tasks, one per thread
    {
        int jl = tid >> 4, c8 = tid & 15;
        *reinterpret_cast<uint4*>(pool + ADJA + jl*136 + c8*8) =
            *reinterpret_cast<const uint4*>(adjT + ((size_t)(b*SS + j0 + jl))*SS + c8*8);
    }

    // ---- agg: C[m=j 32][n=h 128] = adjT x xn_eff, K=i in 2 chunks of 64 ----
    int mt = w & 1, ntb = (w >> 1) * 2;
    vf4 acc[2]; acc[0]=0.f; acc[1]=0.f;
    for (int cs = 0; cs < 2; ++cs){
        for (int task = tid; task < 2048; task += 512){
            int hh = task >> 4, q = task & 15;
            float4 v = *reinterpret_cast<const float4*>(
                xnT + ((size_t)(b*HH + hh))*SS + cs*64 + q*4);
            float2 ss = scsh[hh];
            float e0 = fmaf(v.x, ss.x, ss.y), e1 = fmaf(v.y, ss.x, ss.y);
            float e2 = fmaf(v.z, ss.x, ss.y), e3 = fmaf(v.w, ss.x, ss.y);
            unsigned short h0 = f2bf(e0), h1 = f2bf(e1), h2 = f2bf(e2), h3 = f2bf(e3);
            unsigned int hA = (unsigned int)h0 | ((unsigned int)h1 << 16);
            unsigned int hB = (unsigned int)h2 | ((unsigned int)h3 << 16);
            unsigned short l0 = f2bf(e0 - bf2f(h0)), l1 = f2bf(e1 - bf2f(h1));
            unsigned short l2 = f2bf(e2 - bf2f(h2)), l3 = f2bf(e3 - bf2f(h3));
            unsigned int lA = (unsigned int)l0 | ((unsigned int)l1 << 16);
            unsigned int lB = (unsigned int)l2 | ((unsigned int)l3 << 16);
            *reinterpret_cast<uint2*>(pool + XH + hh*72 + q*4) = make_uint2(hA, hB);
            *reinterpret_cast<uint2*>(pool + XL + hh*72 + q*4) = make_uint2(lA, lB);
        }
        __syncthreads();
        #pragma unroll
        for (int ks = 0; ks < 2; ++ks){
            short8 af = *reinterpret_cast<const short8*>(
                pool + ADJA + (mt*16 + frow)*136 + cs*64 + ks*32 + fk);
            #pragma unroll
            for (int ntl = 0; ntl < 2; ++ntl){
                int nt = ntb + ntl;
                short8 bh = *reinterpret_cast<const short8*>(
                    pool + XH + (nt*16 + frow)*72 + ks*32 + fk);
                short8 bo = *reinterpret_cast<const short8*>(
                    pool + XL + (nt*16 + frow)*72 + ks*32 + fk);
                acc[ntl] = __builtin_amdgcn_mfma_f32_16x16x32_bf16(af, bh, acc[ntl], 0, 0, 0);
                acc[ntl] = __builtin_amdgcn_mfma_f32_16x16x32_bf16(af, bo, acc[ntl], 0, 0, 0);
            }
        }
        __syncthreads();
    }
    // agg epilogue -> AGGH/AGGL [j][c=h]; stage xnJ [j][c] hi/lo (first 256 thr)
    #pragma unroll
    for (int ntl = 0; ntl < 2; ++ntl){
        int hh = (ntb + ntl)*16 + frow;
        #pragma unroll
        for (int r = 0; r < 4; ++r){
            int jl = mt*16 + (lane>>4)*4 + r;
            float v = acc[ntl][r] * dinvL[jl];
            unsigned short hi = f2bf(v);
            pool[AGGH + jl*136 + hh] = hi;
            pool[AGGL + jl*136 + hh] = f2bf(v - bf2f(hi));
        }
    }
    if (tid < 256){
        int jg = tid >> 5, cg = tid & 31;
        float mv[4][4];
        #pragma unroll
        for (int e = 0; e < 4; ++e){
            float4 v = *reinterpret_cast<const float4*>(
                xnT + ((size_t)(b*HH + cg*4 + e))*SS + j0 + jg*4);
            float2 ss = scsh[cg*4 + e];
            mv[e][0]=fmaf(v.x,ss.x,ss.y); mv[e][1]=fmaf(v.y,ss.x,ss.y);
            mv[e][2]=fmaf(v.z,ss.x,ss.y); mv[e][3]=fmaf(v.w,ss.x,ss.y);
        }
        #pragma unroll
        for (int f = 0; f < 4; ++f){
            int jl = jg*4 + f;
            unsigned short h0=f2bf(mv[0][f]), h1=f2bf(mv[1][f]), h2=f2bf(mv[2][f]), h3=f2bf(mv[3][f]);
            unsigned int a0 = (unsigned int)h0 | ((unsigned int)h1<<16);
            unsigned int a1v = (unsigned int)h2 | ((unsigned int)h3<<16);
            unsigned short l0=f2bf(mv[0][f]-bf2f(h0)), l1=f2bf(mv[1][f]-bf2f(h1));
            unsigned short l2=f2bf(mv[2][f]-bf2f(h2)), l3=f2bf(mv[3][f]-bf2f(h3));
            unsigned int b0 = (unsigned int)l0 | ((unsigned int)l1<<16);
            unsigned int b1v = (unsigned int)l2 | ((unsigned int)l3<<16);
            *reinterpret_cast<uint2*>(pool + XNJH + jl*136 + cg*4) = make_uint2(a0, a1v);
            *reinterpret_cast<uint2*>(pool + XNJL + jl*136 + cg*4) = make_uint2(b0, b1v);
        }
    }
    __syncthreads();

    // ---- lin: C[m=h 128][n=j 32] = wlT x agg + wrT x xnJ, K=128 in 4 chunks --
    vf4 lacc[2]; lacc[0]=0.f; lacc[1]=0.f;
    const unsigned short* wptr[4] = {wlH, wlL, wrH, wrL};
    for (int ck = 0; ck < 4; ++ck){
        for (int task = tid; task < 2048; task += 512){
            int mat = task >> 9, hh = (task >> 2) & 127, q = task & 3;
            *reinterpret_cast<uint4*>(pool + LINA + mat*5120 + hh*40 + q*8) =
                *reinterpret_cast<const uint4*>(wptr[mat] + (size_t)hh*128 + ck*32 + q*8);
        }
        __syncthreads();
        #pragma unroll
        for (int mat = 0; mat < 2; ++mat){
            int Ah = LINA + (mat*2)*5120;
            int Al = LINA + (mat*2+1)*5120;
            int Bh = mat ? XNJH : AGGH;
            int Bl = mat ? XNJL : AGGL;
            short8 ah = *reinterpret_cast<const short8*>(pool + Ah + (w*16 + frow)*40 + fk);
            short8 al = *reinterpret_cast<const short8*>(pool + Al + (w*16 + frow)*40 + fk);
            #pragma unroll
            for (int ntl = 0; ntl < 2; ++ntl){
                short8 bh = *reinterpret_cast<const short8*>(
                    pool + Bh + (ntl*16 + frow)*136 + ck*32 + fk);
                short8 bo = *reinterpret_cast<const short8*>(
                    pool + Bl + (ntl*16 + frow)*136 + ck*32 + fk);
                lacc[ntl] = __builtin_amdgcn_mfma_f32_16x16x32_bf16(ah, bh, lacc[ntl], 0,0,0);
                lacc[ntl] = __builtin_amdgcn_mfma_f32_16x16x32_bf16(ah, bo, lacc[ntl], 0,0,0);
                lacc[ntl] = __builtin_amdgcn_mfma_f32_16x16x32_bf16(al, bh, lacc[ntl], 0,0,0);
            }
        }
        __syncthreads();
    }
    // epilogue: bias, store, BN partials via 16-lane shfl reduce (wave-disjoint hh)
    #pragma unroll
    for (int ntl = 0; ntl < 2; ++ntl){
        #pragma unroll
        for (int r = 0; r < 4; ++r){
            int hh = w*16 + (lane>>4)*4 + r;
            int jl = ntl*16 + (lane & 15);
            float v = lacc[ntl][r] + blL[hh];
            outT[((size_t)(b*HH + hh))*SS + j0 + jl] = v;
            float s1 = v, s2 = v*v;
            #pragma unroll
            for (int off = 1; off < 16; off <<= 1){
                s1 += __shfl_xor(s1, off, 64);
                s2 += __shfl_xor(s2, off, 64);
            }
            if ((lane & 15) == 0){ redS[hh].x += s1; redS[hh].y += s2; }
        }
    }
    __syncthreads();
    if (tid < 128){
        atomicAdd(&accL[2*tid],   redS[tid].x);
        atomicAdd(&accL[2*tid+1], redS[tid].y);
    }
}

// ============ K4: head — final BN on lastcols of outT + gate + MLP ============
__global__ __launch_bounds__(128) void k_head(
    const float* __restrict__ t0, const float* __restrict__ t1,
    const float* __restrict__ t2, const float* __restrict__ accf,
    const float* __restrict__ gamma, const float* __restrict__ beta,
    const float* __restrict__ wg, const float* __restrict__ bg,
    const float* __restrict__ we, const float* __restrict__ be,
    const float* __restrict__ wo, const float* __restrict__ bo,
    float* __restrict__ out)
{
    int b = blockIdx.x; int t = threadIdx.x;
    __shared__ float xw[HH];
    const float* outs[3] = {t0, t1, t2};
    float a = bg[0];
    #pragma unroll
    for (int l = 0; l < 3; ++l){
        float2 s = reinterpret_cast<const float2*>(accf)[l*128 + t];
        float m = s.x * (1.f/4096.f);
        float var = fmaxf(s.y * (1.f/4096.f) - m*m, 0.f);
        float sc = gamma[l*128+t] / sqrtf(var + 1e-5f);
        float sh = beta[l*128+t] - m*sc;
        float val = fmaf(outs[l][((size_t)(b*HH + t))*SS + SS-1], sc, sh);
        a = fmaf(val, wg[l], a);
    }
    xw[t] = fmaxf(a, 0.f);
    __syncthreads();
    if (t < 64){
        float acc = be[t];
        for (int h = 0; h < HH; ++h) acc = fmaf(xw[h], we[h*64 + t], acc);
        float h2 = fmaxf(acc, 0.f);
        float r = h2 * wo[t];
        #pragma unroll
        for (int off = 32; off; off >>= 1) r += __shfl_down(r, off, 64);
        if (t == 0) out[b] = r + bo[0];
    }
}

// ==============================================================================
extern "C" void kernel_launch(void* const* d_in, const int* in_sizes, int n_in,
                              void* d_out, int out_size, void* d_ws, size_t ws_size,
                              hipStream_t stream)
{
    const float* data = (const float*)d_in[0];
    const float* gu   = (const float*)d_in[1];
    const float* w11  = (const float*)d_in[2];
    const float* b11  = (const float*)d_in[3];
    const float* w12  = (const float*)d_in[4];
    const float* b12  = (const float*)d_in[5];
    const float* w21  = (const float*)d_in[6];
    const float* b21  = (const float*)d_in[7];
    const float* w22  = (const float*)d_in[8];
    const float* b22  = (const float*)d_in[9];
    const float* w31  = (const float*)d_in[10];
    const float* b31  = (const float*)d_in[11];
    const float* wf   = (const float*)d_in[12];
    const float* bf   = (const float*)d_in[13];
    const float* w1   = (const float*)d_in[14];
    const float* b1   = (const float*)d_in[15];
    const float* w2   = (const float*)d_in[16];
    const float* b2   = (const float*)d_in[17];
    const float* wl   = (const float*)d_in[18];
    const float* bl   = (const float*)d_in[19];
    const float* wr   = (const float*)d_in[20];
    const float* gamma= (const float*)d_in[21];
    const float* beta = (const float*)d_in[22];
    const float* wg   = (const float*)d_in[23];
    const float* bg   = (const float*)d_in[24];
    const float* we   = (const float*)d_in[25];
    const float* be   = (const float*)d_in[26];
    const float* wo   = (const float*)d_in[27];
    const float* bo   = (const float*)d_in[28];
    float* out = (float*)d_out;

    float* ws = (float*)d_ws;
    float* hs   = ws;                          // NBSH
    float* hrT  = ws + (size_t)NBSH;
    float* XT   = ws + (size_t)2*NBSH;
    float* T0   = ws + (size_t)3*NBSH;
    float* T1   = ws + (size_t)4*NBSH;
    float* T2   = ws + (size_t)5*NBSH;
    float* G    = ws + (size_t)6*NBSH;
    float* W3    = G;                          // 6144
    float* W5    = G + 6144;                   // 10240
    float* W31T  = G + 16384;                  // 2048
    float* Beff1 = G + 18432;                  // 384
    float* Beff2 = G + 18816;                  // 640
    float* accf  = G + 19456;                  // 768
    float* dinv  = G + 20224;                  // 4096
    unsigned short* adjTG = (unsigned short*)(G + 24320);           // 524288 us
    unsigned short* wHi   = (unsigned short*)(G + 24320 + 262144);  // 98304 us
    unsigned short* wLo   = (unsigned short*)(G + 24320 + 262144 + 49152);

    k_prep<<<40, 256, 0, stream>>>(w12, w22, w31, w11, b11, w21, b21, wl, wr,
                                   W3, W5, W31T, Beff1, Beff2, accf, wHi, wLo);
    k_fuse_all<<<256, 256, 0, stream>>>(data, W3, W5, W31T, Beff1, Beff2,
                                        b12, b22, b31, wf, bf, w1, b1,
                                        hs, hrT, XT);
    k_adj<<<512, 256, 0, stream>>>(hs, hrT, w2, b2, gu, adjTG, dinv);

    const float* xnTs[3] = {XT, T0, T1};
    float*       outs[3] = {T0, T1, T2};
    for (int l = 0; l < 3; ++l){
        int aff = (l > 0);
        const float* gP = gamma + (l>0 ? (l-1)*HH : 0);
        const float* bP = beta  + (l>0 ? (l-1)*HH : 0);
        const float* aP = accf + (l>0 ? (l-1)*256 : 0);
        k_gnn<<<128, 512, 0, stream>>>(adjTG, xnTs[l], dinv, gP, bP, aP, aff,
            wHi + (size_t)l*16384, wLo + (size_t)l*16384,
            wHi + (size_t)(3+l)*16384, wLo + (size_t)(3+l)*16384,
            bl + (size_t)l*HH, outs[l], accf + (size_t)l*256);
    }
    k_head<<<BB, 128, 0, stream>>>(T0, T1, T2, accf, gamma, beta,
                                   wg, bg, we, be, wo, bo, out);
}

// Round 14
// 130.566 us; speedup vs baseline: 1.8514x; 1.0867x over previous
//
#include <hip/hip_runtime.h>
#include <math.h>

#define BB 32
#define SS 128
#define DIN 16
#define HH 128
#define NBSH (BB*SS*HH)   // 524288

typedef __attribute__((ext_vector_type(8))) short short8;
typedef __attribute__((ext_vector_type(4))) float vf4;

__device__ __forceinline__ unsigned short f2bf(float x){
    union { float f; unsigned int u; } v; v.f = x;
    unsigned int r = v.u + 0x7FFF + ((v.u >> 16) & 1);
    return (unsigned short)(r >> 16);
}
__device__ __forceinline__ float bf2f(unsigned short b){
    union { unsigned int u; float f; } v; v.u = ((unsigned int)b) << 16;
    return v.f;
}

// ============ K0: prep — composite conv weights + transposed bf16 splits ======
__global__ __launch_bounds__(256) void k_prep(
    const float* __restrict__ w12, const float* __restrict__ w22,
    const float* __restrict__ w31,
    const float* __restrict__ w11, const float* __restrict__ b11,
    const float* __restrict__ w21, const float* __restrict__ b21,
    const float* __restrict__ wl, const float* __restrict__ wr,
    const float* __restrict__ wf, const float* __restrict__ w1,
    float* __restrict__ W3, float* __restrict__ W5, float* __restrict__ W31T,
    float* __restrict__ Beff1, float* __restrict__ Beff2, float* __restrict__ accf,
    unsigned short* __restrict__ wHi, unsigned short* __restrict__ wLo,
    unsigned short* __restrict__ wfTH, unsigned short* __restrict__ wfTL,
    unsigned short* __restrict__ w1sTH, unsigned short* __restrict__ w1sTL,
    unsigned short* __restrict__ w1rTH, unsigned short* __restrict__ w1rTL)
{
    __shared__ float W12L[8*384];
    __shared__ float W22L[8*640];
    __shared__ float w11L[2048], w21L[2048], b11L[128], b21L[128];
    __shared__ float S[4096];
    int blk = blockIdx.x; int tid = threadIdx.x;

    if (blk < 16){
        int h0 = blk*8;
        for (int i = tid; i < 768; i += 256){
            int hl = i/96, o4 = i%96;
            *reinterpret_cast<float4*>(W12L + hl*384 + o4*4) =
                reinterpret_cast<const float4*>(w12)[(h0+hl)*96 + o4];
        }
        for (int i = tid; i < 1280; i += 256){
            int hl = i/160, o4 = i%160;
            *reinterpret_cast<float4*>(W22L + hl*640 + o4*4) =
                reinterpret_cast<const float4*>(w22)[(h0+hl)*160 + o4];
        }
        for (int i = tid; i < 512; i += 256)
            *reinterpret_cast<float4*>(w11L + i*4) = reinterpret_cast<const float4*>(w11)[i];
        for (int i = tid; i < 512; i += 256)
            *reinterpret_cast<float4*>(w21L + i*4) = reinterpret_cast<const float4*>(w21)[i];
        if (tid < 128){ b11L[tid] = b11[tid]; b21L[tid] = b21[tid]; }
        if (blk == 0){ for (int i = tid; i < 768; i += 256) accf[i] = 0.f; }
        __syncthreads();

        for (int T = tid; T < 1216; T += 256){
            if (T < 384){
                int hl = T/48, kd = T%48, k = kd>>4, d = kd&15;
                float a = 0.f;
                #pragma unroll 4
                for (int c = 0; c < HH; ++c) a = fmaf(W12L[hl*384 + c*3 + k], w11L[c*16 + d], a);
                W3[(k*16+d)*128 + h0+hl] = a;
            } else if (T < 1024){
                int tt = T-384, hl = tt/80, kd = tt%80, k = kd>>4, d = kd&15;
                float a = 0.f;
                #pragma unroll 4
                for (int c = 0; c < HH; ++c) a = fmaf(W22L[hl*640 + c*5 + k], w21L[c*16 + d], a);
                W5[(k*16+d)*128 + h0+hl] = a;
            } else if (T < 1048){
                int tt = T-1024, hl = tt/3, k = tt%3;
                float a = 0.f;
                #pragma unroll 4
                for (int c = 0; c < HH; ++c) a = fmaf(W12L[hl*384 + c*3 + k], b11L[c], a);
                Beff1[k*128 + h0+hl] = a;
            } else if (T < 1088){
                int tt = T-1048, hl = tt/5, k = tt%5;
                float a = 0.f;
                #pragma unroll 4
                for (int c = 0; c < HH; ++c) a = fmaf(W22L[hl*640 + c*5 + k], b21L[c], a);
                Beff2[k*128 + h0+hl] = a;
            } else {
                int tt = T-1088, hl = tt>>4, d = tt&15;
                W31T[d*128 + h0+hl] = w31[(h0+hl)*16 + d];
            }
        }
    } else if (blk < 40){
        int q = blk - 16;          // 0..23
        int h = tid & 127; int half = tid >> 7;
        for (int rl = half; rl < 32; rl += 2){
            int r = q*32 + rl;     // 0..767
            int m = r >> 7;
            int c = r & 127;
            const float* src = (m < 3) ? (wl + (size_t)m*16384) : (wr + (size_t)(m-3)*16384);
            float v = src[c*128 + h];
            unsigned short hi = f2bf(v);
            unsigned short lo = f2bf(v - bf2f(hi));
            wHi[(size_t)m*16384 + h*128 + c] = hi;
            wLo[(size_t)m*16384 + h*128 + c] = lo;
        }
    } else {
        // transpose + hi/lo split for wf (384x128) and w1 halves (128x128 each)
        int t2 = blk - 40;         // 0..19
        const float* src; unsigned short *dH, *dL; int kbase, rstride;
        if (t2 < 12){ src = wf + (size_t)t2*32*128; dH = wfTH; dL = wfTL; kbase = t2*32; rstride = 384; }
        else if (t2 < 16){ int c = t2-12; src = w1 + (size_t)c*32*128; dH = w1sTH; dL = w1sTL; kbase = c*32; rstride = 128; }
        else { int c = t2-16; src = w1 + 16384 + (size_t)c*32*128; dH = w1rTH; dL = w1rTL; kbase = c*32; rstride = 128; }
        for (int i = tid; i < 1024; i += 256)
            reinterpret_cast<float4*>(S)[i] = reinterpret_cast<const float4*>(src)[i];
        __syncthreads();
        for (int task = tid; task < 4096; task += 256){
            int h = task & 127, kl = task >> 7;   // kl 0..31
            float v = S[kl*128 + h];
            unsigned short hi = f2bf(v);
            dH[(size_t)h*rstride + kbase + kl] = hi;
            dL[(size_t)h*rstride + kbase + kl] = f2bf(v - bf2f(hi));
        }
    }
}

// ============ K1: conv fp32 -> MFMA fuse (4-product bf16) -> MFMA hs/hr =======
// 256 blocks x 512 thr (8 waves); block = 16 rows of one batch b.
#define AHo 0
#define ALo 6272
#define BHo 12544
#define BLo 17664
#define xHo 22784
#define xLo 24960
__global__ __launch_bounds__(512) void k_fuse_all(
    const float* __restrict__ data,
    const float* __restrict__ W3, const float* __restrict__ W5,
    const float* __restrict__ W31T,
    const float* __restrict__ Beff1, const float* __restrict__ Beff2,
    const float* __restrict__ b12, const float* __restrict__ b22,
    const float* __restrict__ b31,
    const unsigned short* __restrict__ wfTH, const unsigned short* __restrict__ wfTL,
    const float* __restrict__ bf,
    const unsigned short* __restrict__ w1sTH, const unsigned short* __restrict__ w1sTL,
    const unsigned short* __restrict__ w1rTH, const unsigned short* __restrict__ w1rTL,
    const float* __restrict__ b1,
    float* __restrict__ hs, float* __restrict__ hrT, float* __restrict__ XT)
{
    __shared__ __align__(16) unsigned short pool[27136];   // 54.3 KB
    __shared__ __align__(16) float dinT[16*40];
    __shared__ float bfL[128], b1L[128];
    int blk = blockIdx.x; int row0 = blk*16;
    int b = row0 >> 7; int s0 = row0 & 127;
    int tid = threadIdx.x; int lane = tid & 63; int w = tid >> 6;      // 8 waves
    int h = tid & 127; int quarter = tid >> 7;                        // conv mapping
    int frow = lane & 15, fk = (lane >> 4) * 8;

    // FIX (round-13 bug): stage FULL 36-row halo (conv5 taps reach r=35), not 29.
    for (int idx = tid; idx < 576; idx += 512){
        int r = idx >> 4, d = idx & 15;
        int sp = s0 - 10 + r;
        dinT[d*40 + r] = (sp >= 0 && sp < SS) ? data[(b*SS+sp)*DIN + d] : 0.f;
    }
    if (tid < 128){ bfL[tid] = bf[tid]; b1L[tid] = b1[tid]; }
    __syncthreads();

    // ---- conv fp32: thread = channel h, rows quarter*4 .. +3 ----
    float a1[4] = {0,0,0,0}, a2[4] = {0,0,0,0}, a3[4] = {0,0,0,0};
    int rb = quarter*4;
    for (int d = 0; d < DIN; ++d){
        float w3v[3], w5v[5];
        #pragma unroll
        for (int k = 0; k < 3; ++k) w3v[k] = W3[(k*DIN+d)*HH + h];
        #pragma unroll
        for (int k = 0; k < 5; ++k) w5v[k] = W5[(k*DIN+d)*HH + h];
        float w31v = W31T[d*HH + h];
        const float4* qp = reinterpret_cast<const float4*>(dinT + d*40 + rb);
        float4 q0=qp[0],q1=qp[1],q2=qp[2],q3=qp[3],q4=qp[4],q5=qp[5];
        float qf[24] = {q0.x,q0.y,q0.z,q0.w, q1.x,q1.y,q1.z,q1.w,
                        q2.x,q2.y,q2.z,q2.w, q3.x,q3.y,q3.z,q3.w,
                        q4.x,q4.y,q4.z,q4.w, q5.x,q5.y,q5.z,q5.w};
        #pragma unroll
        for (int tp = 0; tp < 4; ++tp){
            #pragma unroll
            for (int k = 0; k < 3; ++k) a1[tp] = fmaf(qf[tp+3*k+7], w3v[k], a1[tp]);
            #pragma unroll
            for (int k = 0; k < 5; ++k) a2[tp] = fmaf(qf[tp+5*k], w5v[k], a2[tp]);
            a3[tp] = fmaf(qf[tp+10], w31v, a3[tp]);
        }
    }
    {
        float be1[3] = {Beff1[h], Beff1[HH+h], Beff1[2*HH+h]};
        float be2[5] = {Beff2[h], Beff2[HH+h], Beff2[2*HH+h], Beff2[3*HH+h], Beff2[4*HH+h]};
        float bv12 = b12[h], bv22 = b22[h], bv31 = b31[h];
        #pragma unroll
        for (int tp = 0; tp < 4; ++tp){
            int rl = rb + tp;
            int s = s0 + rl;
            float v1 = a1[tp] + bv12;
            #pragma unroll
            for (int k = 0; k < 3; ++k)
                if ((unsigned)(s + 3*k - 3) < SS) v1 += be1[k];
            float v2 = a2[tp] + bv22;
            #pragma unroll
            for (int k = 0; k < 5; ++k)
                if ((unsigned)(s + 5*k - 10) < SS) v2 += be2[k];
            float v3 = a3[tp] + bv31;
            unsigned short h1 = f2bf(v1), h2 = f2bf(v2), h3 = f2bf(v3);
            pool[AHo + rl*392 + h]        = h1;
            pool[AHo + rl*392 + 128 + h]  = h2;
            pool[AHo + rl*392 + 256 + h]  = h3;
            pool[ALo + rl*392 + h]        = f2bf(v1 - bf2f(h1));
            pool[ALo + rl*392 + 128 + h]  = f2bf(v2 - bf2f(h2));
            pool[ALo + rl*392 + 256 + h]  = f2bf(v3 - bf2f(h3));
        }
    }
    __syncthreads();

    // ---- fuse GEMM via MFMA: C[m=16 rows][n=128] = A(16x384) x wfT, 4-product -
    vf4 facc; facc = 0.f;
    for (int ch = 0; ch < 12; ++ch){
        int ck0 = ch*32;
        for (int task = tid; task < 1024; task += 512){
            int isL = task >> 9; int n = (task >> 2) & 127; int q = task & 3;
            const unsigned short* srcw = isL ? wfTL : wfTH;
            unsigned short* dst = pool + (isL ? BLo : BHo);
            *reinterpret_cast<uint4*>(dst + n*40 + q*8) =
                *reinterpret_cast<const uint4*>(srcw + (size_t)n*384 + ck0 + q*8);
        }
        __syncthreads();
        short8 ah = *reinterpret_cast<const short8*>(pool + AHo + frow*392 + ck0 + fk);
        short8 al = *reinterpret_cast<const short8*>(pool + ALo + frow*392 + ck0 + fk);
        short8 bh = *reinterpret_cast<const short8*>(pool + BHo + (w*16+frow)*40 + fk);
        short8 bl = *reinterpret_cast<const short8*>(pool + BLo + (w*16+frow)*40 + fk);
        facc = __builtin_amdgcn_mfma_f32_16x16x32_bf16(ah, bh, facc, 0,0,0);
        facc = __builtin_amdgcn_mfma_f32_16x16x32_bf16(ah, bl, facc, 0,0,0);
        facc = __builtin_amdgcn_mfma_f32_16x16x32_bf16(al, bh, facc, 0,0,0);
        facc = __builtin_amdgcn_mfma_f32_16x16x32_bf16(al, bl, facc, 0,0,0);
        __syncthreads();
    }
    // relu + bias -> xH/xL [m][k=h]
    {
        int n_col = w*16 + (lane & 15);
        float bfv = bfL[n_col];
        #pragma unroll
        for (int r = 0; r < 4; ++r){
            int m = (lane>>4)*4 + r;
            float v = fmaxf(facc[r] + bfv, 0.f);
            unsigned short hi = f2bf(v);
            pool[xHo + m*136 + n_col] = hi;
            pool[xLo + m*136 + n_col] = f2bf(v - bf2f(hi));
        }
    }
    __syncthreads();
    // XT global write (coalesced): x = hi+lo reconstruction
    for (int task = tid; task < 2048; task += 512){
        int m = task & 15, c = task >> 4;
        float v = bf2f(pool[xHo + m*136 + c]) + bf2f(pool[xLo + m*136 + c]);
        XT[((size_t)(b*HH + c))*SS + s0 + m] = v;
    }

    // ---- hs/hr via MFMA: C[m=16][n=128] = x(16x128) x w1T, 4-product ----
    vf4 as, ar; as = 0.f; ar = 0.f;
    for (int pass = 0; pass < 2; ++pass){
        const unsigned short* sH = pass ? w1rTH : w1sTH;
        const unsigned short* sL = pass ? w1rTL : w1sTL;
        vf4 acc; acc = 0.f;
        for (int ch = 0; ch < 4; ++ch){
            int ck0 = ch*32;
            for (int task = tid; task < 1024; task += 512){
                int isL = task >> 9; int n = (task >> 2) & 127; int q = task & 3;
                const unsigned short* srcw = isL ? sL : sH;
                unsigned short* dst = pool + (isL ? BLo : BHo);
                *reinterpret_cast<uint4*>(dst + n*40 + q*8) =
                    *reinterpret_cast<const uint4*>(srcw + (size_t)n*128 + ck0 + q*8);
            }
            __syncthreads();
            short8 ah = *reinterpret_cast<const short8*>(pool + xHo + frow*136 + ck0 + fk);
            short8 al = *reinterpret_cast<const short8*>(pool + xLo + frow*136 + ck0 + fk);
            short8 bh = *reinterpret_cast<const short8*>(pool + BHo + (w*16+frow)*40 + fk);
            short8 bl = *reinterpret_cast<const short8*>(pool + BLo + (w*16+frow)*40 + fk);
            acc = __builtin_amdgcn_mfma_f32_16x16x32_bf16(ah, bh, acc, 0,0,0);
            acc = __builtin_amdgcn_mfma_f32_16x16x32_bf16(ah, bl, acc, 0,0,0);
            acc = __builtin_amdgcn_mfma_f32_16x16x32_bf16(al, bh, acc, 0,0,0);
            acc = __builtin_amdgcn_mfma_f32_16x16x32_bf16(al, bl, acc, 0,0,0);
            __syncthreads();
        }
        if (pass == 0) as = acc; else ar = acc;
    }
    {
        int n_col = w*16 + (lane & 15);
        float b1v = b1L[n_col];
        #pragma unroll
        for (int r = 0; r < 4; ++r){
            int m = (lane>>4)*4 + r;
            hs[(size_t)(row0+m)*128 + n_col] = as[r];
            hrT[((size_t)(b*HH + n_col))*SS + s0 + m] = ar[r] + b1v;
        }
    }
}

// ============ K2: edge logits + argmax; emits adjT (bf16) + deginv ============
__global__ __launch_bounds__(256) void k_adj(
    const float* __restrict__ hs, const float* __restrict__ hrT,
    const float* __restrict__ w2, const float* __restrict__ b2,
    const float* __restrict__ gu, unsigned short* __restrict__ adjT,
    float* __restrict__ deginv)
{
    int blk = blockIdx.x; int b = blk >> 4; int j0 = (blk & 15) * 8;
    int tid = threadIdx.x; int i = tid & 127; int g = tid >> 7;
    __shared__ float hsL[8][128];
    __shared__ float w20L[128], w21L[128];
    __shared__ int degS[8];
    for (int idx = tid; idx < 1024; idx += 256){
        int jj = idx >> 7, h = idx & 127;
        hsL[jj][h] = hs[(size_t)(b*SS + j0 + jj)*HH + h];
    }
    if (tid < 128){ w20L[tid] = w2[tid*2]; w21L[tid] = w2[tid*2+1]; }
    if (tid < 8) degS[tid] = 0;
    __syncthreads();
    float d0[4] = {0,0,0,0}, d1[4] = {0,0,0,0};
    const float* hrb = hrT + (size_t)b*HH*SS + i;
    #pragma unroll 4
    for (int h = 0; h < 128; ++h){
        float hrv = hrb[(size_t)h*SS];
        float wa = w20L[h], wb = w21L[h];
        float r0 = fmaxf(hsL[g*4+0][h] + hrv, 0.f);
        float r1 = fmaxf(hsL[g*4+1][h] + hrv, 0.f);
        float r2 = fmaxf(hsL[g*4+2][h] + hrv, 0.f);
        float r3 = fmaxf(hsL[g*4+3][h] + hrv, 0.f);
        d0[0]=fmaf(r0,wa,d0[0]); d1[0]=fmaf(r0,wb,d1[0]);
        d0[1]=fmaf(r1,wa,d0[1]); d1[1]=fmaf(r1,wb,d1[1]);
        d0[2]=fmaf(r2,wa,d0[2]); d1[2]=fmaf(r2,wb,d1[2]);
        d0[3]=fmaf(r3,wa,d0[3]); d1[3]=fmaf(r3,wb,d1[3]);
    }
    float b20 = b2[0], b21 = b2[1];
    #pragma unroll
    for (int jj = 0; jj < 4; ++jj){
        int j = j0 + g*4 + jj;
        size_t e = (size_t)(b*SS + i)*SS + j;
        float2 uv = *reinterpret_cast<const float2*>(gu + e*2);
        float u0 = fminf(fmaxf(uv.x, 1e-6f), 0.999999f);
        float u1 = fminf(fmaxf(uv.y, 1e-6f), 0.999999f);
        float g0 = -logf(-logf(u0));
        float g1 = -logf(-logf(u1));
        float y0 = d0[jj] + b20 + g0;
        float y1 = d1[jj] + b21 + g1;
        bool av = (j > i) && (y0 >= y1);
        adjT[(size_t)(b*SS + j)*SS + i] = av ? (unsigned short)0x3F80 : (unsigned short)0;
        unsigned long long msk = __ballot(av);
        if ((tid & 63) == 0) atomicAdd(&degS[g*4+jj], (int)__popcll(msk));
    }
    __syncthreads();
    if (tid < 8) deginv[b*SS + j0 + tid] = 1.f / fmaxf((float)degS[tid], 1.f);
}

// ============ K3: MFMA GNN block, 512 threads (8 waves) =======================
#define AGGH 0
#define AGGL 4352
#define ADJA 8704
#define XH   13056
#define XL   22272
#define LINA 8704
#define XNJH 29184
#define XNJL 33536
__global__ __launch_bounds__(512) void k_gnn(
    const unsigned short* __restrict__ adjT, const float* __restrict__ xnT,
    const float* __restrict__ deginv,
    const float* __restrict__ gammaP, const float* __restrict__ betaP,
    const float* __restrict__ accP, int aff,
    const unsigned short* __restrict__ wlH, const unsigned short* __restrict__ wlL,
    const unsigned short* __restrict__ wrH, const unsigned short* __restrict__ wrL,
    const float* __restrict__ bl,
    float* __restrict__ outT, float* __restrict__ accL)
{
    __shared__ __align__(16) unsigned short pool[37888];
    __shared__ float2 scsh[128];
    __shared__ float dinvL[32];
    __shared__ float2 redS[128];
    __shared__ float blL[128];
    int blk = blockIdx.x; int b = blk >> 2; int j0 = (blk & 3) * 32;
    int tid = threadIdx.x; int lane = tid & 63; int w = tid >> 6;
    int frow = lane & 15, fk = (lane >> 4) * 8;

    if (tid < 128){
        if (aff){
            float2 s = reinterpret_cast<const float2*>(accP)[tid];
            float m = s.x * (1.f/4096.f);
            float var = fmaxf(s.y * (1.f/4096.f) - m*m, 0.f);
            float sc = gammaP[tid] / sqrtf(var + 1e-5f);
            scsh[tid] = make_float2(sc, betaP[tid] - m*sc);
        } else scsh[tid] = make_float2(1.f, 0.f);
        redS[tid] = make_float2(0.f, 0.f);
        blL[tid] = bl[tid];
    }
    if (tid < 32) dinvL[tid] = deginv[b*SS + j0 + tid];
    __syncthreads();

    {
        int jl = tid >> 4, c8 = tid & 15;
        *reinterpret_cast<uint4*>(pool + ADJA + jl*136 + c8*8) =
            *reinterpret_cast<const uint4*>(adjT + ((size_t)(b*SS + j0 + jl))*SS + c8*8);
    }

    int mt = w & 1, ntb = (w >> 1) * 2;
    vf4 acc[2]; acc[0]=0.f; acc[1]=0.f;
    for (int cs = 0; cs < 2; ++cs){
        for (int task = tid; task < 2048; task += 512){
            int hh = task >> 4, q = task & 15;
            float4 v = *reinterpret_cast<const float4*>(
                xnT + ((size_t)(b*HH + hh))*SS + cs*64 + q*4);
            float2 ss = scsh[hh];
            float e0 = fmaf(v.x, ss.x, ss.y), e1 = fmaf(v.y, ss.x, ss.y);
            float e2 = fmaf(v.z, ss.x, ss.y), e3 = fmaf(v.w, ss.x, ss.y);
            unsigned short h0 = f2bf(e0), h1 = f2bf(e1), h2 = f2bf(e2), h3 = f2bf(e3);
            unsigned int hA = (unsigned int)h0 | ((unsigned int)h1 << 16);
            unsigned int hB = (unsigned int)h2 | ((unsigned int)h3 << 16);
            unsigned short l0 = f2bf(e0 - bf2f(h0)), l1 = f2bf(e1 - bf2f(h1));
            unsigned short l2 = f2bf(e2 - bf2f(h2)), l3 = f2bf(e3 - bf2f(h3));
            unsigned int lA = (unsigned int)l0 | ((unsigned int)l1 << 16);
            unsigned int lB = (unsigned int)l2 | ((unsigned int)l3 << 16);
            *reinterpret_cast<uint2*>(pool + XH + hh*72 + q*4) = make_uint2(hA, hB);
            *reinterpret_cast<uint2*>(pool + XL + hh*72 + q*4) = make_uint2(lA, lB);
        }
        __syncthreads();
        #pragma unroll
        for (int ks = 0; ks < 2; ++ks){
            short8 af = *reinterpret_cast<const short8*>(
                pool + ADJA + (mt*16 + frow)*136 + cs*64 + ks*32 + fk);
            #pragma unroll
            for (int ntl = 0; ntl < 2; ++ntl){
                int nt = ntb + ntl;
                short8 bh = *reinterpret_cast<const short8*>(
                    pool + XH + (nt*16 + frow)*72 + ks*32 + fk);
                short8 bo = *reinterpret_cast<const short8*>(
                    pool + XL + (nt*16 + frow)*72 + ks*32 + fk);
                acc[ntl] = __builtin_amdgcn_mfma_f32_16x16x32_bf16(af, bh, acc[ntl], 0, 0, 0);
                acc[ntl] = __builtin_amdgcn_mfma_f32_16x16x32_bf16(af, bo, acc[ntl], 0, 0, 0);
            }
        }
        __syncthreads();
    }
    #pragma unroll
    for (int ntl = 0; ntl < 2; ++ntl){
        int hh = (ntb + ntl)*16 + frow;
        #pragma unroll
        for (int r = 0; r < 4; ++r){
            int jl = mt*16 + (lane>>4)*4 + r;
            float v = acc[ntl][r] * dinvL[jl];
            unsigned short hi = f2bf(v);
            pool[AGGH + jl*136 + hh] = hi;
            pool[AGGL + jl*136 + hh] = f2bf(v - bf2f(hi));
        }
    }
    if (tid < 256){
        int jg = tid >> 5, cg = tid & 31;
        float mv[4][4];
        #pragma unroll
        for (int e = 0; e < 4; ++e){
            float4 v = *reinterpret_cast<const float4*>(
                xnT + ((size_t)(b*HH + cg*4 + e))*SS + j0 + jg*4);
            float2 ss = scsh[cg*4 + e];
            mv[e][0]=fmaf(v.x,ss.x,ss.y); mv[e][1]=fmaf(v.y,ss.x,ss.y);
            mv[e][2]=fmaf(v.z,ss.x,ss.y); mv[e][3]=fmaf(v.w,ss.x,ss.y);
        }
        #pragma unroll
        for (int f = 0; f < 4; ++f){
            int jl = jg*4 + f;
            unsigned short h0=f2bf(mv[0][f]), h1=f2bf(mv[1][f]), h2=f2bf(mv[2][f]), h3=f2bf(mv[3][f]);
            unsigned int a0 = (unsigned int)h0 | ((unsigned int)h1<<16);
            unsigned int a1v = (unsigned int)h2 | ((unsigned int)h3<<16);
            unsigned short l0=f2bf(mv[0][f]-bf2f(h0)), l1=f2bf(mv[1][f]-bf2f(h1));
            unsigned short l2=f2bf(mv[2][f]-bf2f(h2)), l3=f2bf(mv[3][f]-bf2f(h3));
            unsigned int b0 = (unsigned int)l0 | ((unsigned int)l1<<16);
            unsigned int b1v = (unsigned int)l2 | ((unsigned int)l3<<16);
            *reinterpret_cast<uint2*>(pool + XNJH + jl*136 + cg*4) = make_uint2(a0, a1v);
            *reinterpret_cast<uint2*>(pool + XNJL + jl*136 + cg*4) = make_uint2(b0, b1v);
        }
    }
    __syncthreads();

    vf4 lacc[2]; lacc[0]=0.f; lacc[1]=0.f;
    const unsigned short* wptr[4] = {wlH, wlL, wrH, wrL};
    for (int ck = 0; ck < 4; ++ck){
        for (int task = tid; task < 2048; task += 512){
            int mat = task >> 9, hh = (task >> 2) & 127, q = task & 3;
            *reinterpret_cast<uint4*>(pool + LINA + mat*5120 + hh*40 + q*8) =
                *reinterpret_cast<const uint4*>(wptr[mat] + (size_t)hh*128 + ck*32 + q*8);
        }
        __syncthreads();
        #pragma unroll
        for (int mat = 0; mat < 2; ++mat){
            int Ah = LINA + (mat*2)*5120;
            int Al = LINA + (mat*2+1)*5120;
            int Bh = mat ? XNJH : AGGH;
            int Bl = mat ? XNJL : AGGL;
            short8 ah = *reinterpret_cast<const short8*>(pool + Ah + (w*16 + frow)*40 + fk);
            short8 al = *reinterpret_cast<const short8*>(pool + Al + (w*16 + frow)*40 + fk);
            #pragma unroll
            for (int ntl = 0; ntl < 2; ++ntl){
                short8 bh = *reinterpret_cast<const short8*>(
                    pool + Bh + (ntl*16 + frow)*136 + ck*32 + fk);
                short8 bo = *reinterpret_cast<const short8*>(
                    pool + Bl + (ntl*16 + frow)*136 + ck*32 + fk);
                lacc[ntl] = __builtin_amdgcn_mfma_f32_16x16x32_bf16(ah, bh, lacc[ntl], 0,0,0);
                lacc[ntl] = __builtin_amdgcn_mfma_f32_16x16x32_bf16(ah, bo, lacc[ntl], 0,0,0);
                lacc[ntl] = __builtin_amdgcn_mfma_f32_16x16x32_bf16(al, bh, lacc[ntl], 0,0,0);
            }
        }
        __syncthreads();
    }
    #pragma unroll
    for (int ntl = 0; ntl < 2; ++ntl){
        #pragma unroll
        for (int r = 0; r < 4; ++r){
            int hh = w*16 + (lane>>4)*4 + r;
            int jl = ntl*16 + (lane & 15);
            float v = lacc[ntl][r] + blL[hh];
            outT[((size_t)(b*HH + hh))*SS + j0 + jl] = v;
            float s1 = v, s2 = v*v;
            #pragma unroll
            for (int off = 1; off < 16; off <<= 1){
                s1 += __shfl_xor(s1, off, 64);
                s2 += __shfl_xor(s2, off, 64);
            }
            if ((lane & 15) == 0){ redS[hh].x += s1; redS[hh].y += s2; }
        }
    }
    __syncthreads();
    if (tid < 128){
        atomicAdd(&accL[2*tid],   redS[tid].x);
        atomicAdd(&accL[2*tid+1], redS[tid].y);
    }
}

// ============ K4: head ========================================================
__global__ __launch_bounds__(128) void k_head(
    const float* __restrict__ t0, const float* __restrict__ t1,
    const float* __restrict__ t2, const float* __restrict__ accf,
    const float* __restrict__ gamma, const float* __restrict__ beta,
    const float* __restrict__ wg, const float* __restrict__ bg,
    const float* __restrict__ we, const float* __restrict__ be,
    const float* __restrict__ wo, const float* __restrict__ bo,
    float* __restrict__ out)
{
    int b = blockIdx.x; int t = threadIdx.x;
    __shared__ float xw[HH];
    const float* outs[3] = {t0, t1, t2};
    float a = bg[0];
    #pragma unroll
    for (int l = 0; l < 3; ++l){
        float2 s = reinterpret_cast<const float2*>(accf)[l*128 + t];
        float m = s.x * (1.f/4096.f);
        float var = fmaxf(s.y * (1.f/4096.f) - m*m, 0.f);
        float sc = gamma[l*128+t] / sqrtf(var + 1e-5f);
        float sh = beta[l*128+t] - m*sc;
        float val = fmaf(outs[l][((size_t)(b*HH + t))*SS + SS-1], sc, sh);
        a = fmaf(val, wg[l], a);
    }
    xw[t] = fmaxf(a, 0.f);
    __syncthreads();
    if (t < 64){
        float acc = be[t];
        for (int h = 0; h < HH; ++h) acc = fmaf(xw[h], we[h*64 + t], acc);
        float h2 = fmaxf(acc, 0.f);
        float r = h2 * wo[t];
        #pragma unroll
        for (int off = 32; off; off >>= 1) r += __shfl_down(r, off, 64);
        if (t == 0) out[b] = r + bo[0];
    }
}

// ==============================================================================
extern "C" void kernel_launch(void* const* d_in, const int* in_sizes, int n_in,
                              void* d_out, int out_size, void* d_ws, size_t ws_size,
                              hipStream_t stream)
{
    const float* data = (const float*)d_in[0];
    const float* gu   = (const float*)d_in[1];
    const float* w11  = (const float*)d_in[2];
    const float* b11  = (const float*)d_in[3];
    const float* w12  = (const float*)d_in[4];
    const float* b12  = (const float*)d_in[5];
    const float* w21  = (const float*)d_in[6];
    const float* b21  = (const float*)d_in[7];
    const float* w22  = (const float*)d_in[8];
    const float* b22  = (const float*)d_in[9];
    const float* w31  = (const float*)d_in[10];
    const float* b31  = (const float*)d_in[11];
    const float* wf   = (const float*)d_in[12];
    const float* bf   = (const float*)d_in[13];
    const float* w1   = (const float*)d_in[14];
    const float* b1   = (const float*)d_in[15];
    const float* w2   = (const float*)d_in[16];
    const float* b2   = (const float*)d_in[17];
    const float* wl   = (const float*)d_in[18];
    const float* bl   = (const float*)d_in[19];
    const float* wr   = (const float*)d_in[20];
    const float* gamma= (const float*)d_in[21];
    const float* beta = (const float*)d_in[22];
    const float* wg   = (const float*)d_in[23];
    const float* bg   = (const float*)d_in[24];
    const float* we   = (const float*)d_in[25];
    const float* be   = (const float*)d_in[26];
    const float* wo   = (const float*)d_in[27];
    const float* bo   = (const float*)d_in[28];
    float* out = (float*)d_out;

    float* ws = (float*)d_ws;
    float* hs   = ws;                          // NBSH
    float* hrT  = ws + (size_t)NBSH;
    float* XT   = ws + (size_t)2*NBSH;
    float* T0   = ws + (size_t)3*NBSH;
    float* T1   = ws + (size_t)4*NBSH;
    float* T2   = ws + (size_t)5*NBSH;
    float* G    = ws + (size_t)6*NBSH;
    float* W3    = G;                          // 6144
    float* W5    = G + 6144;                   // 10240
    float* W31T  = G + 16384;                  // 2048
    float* Beff1 = G + 18432;                  // 384
    float* Beff2 = G + 18816;                  // 640
    float* accf  = G + 19456;                  // 768
    float* dinv  = G + 20224;                  // 4096
    unsigned short* adjTG = (unsigned short*)(G + 24320);           // 262144 fl
    unsigned short* wHi   = (unsigned short*)(G + 286464);          // 49152 fl
    unsigned short* wLo   = (unsigned short*)(G + 335616);          // 49152 fl
    unsigned short* wfTH  = (unsigned short*)(G + 384768);          // 24576 fl
    unsigned short* wfTL  = (unsigned short*)(G + 409344);
    unsigned short* w1sTH = (unsigned short*)(G + 433920);          // 8192 fl
    unsigned short* w1sTL = (unsigned short*)(G + 442112);
    unsigned short* w1rTH = (unsigned short*)(G + 450304);
    unsigned short* w1rTL = (unsigned short*)(G + 458496);

    k_prep<<<60, 256, 0, stream>>>(w12, w22, w31, w11, b11, w21, b21, wl, wr,
                                   wf, w1,
                                   W3, W5, W31T, Beff1, Beff2, accf, wHi, wLo,
                                   wfTH, wfTL, w1sTH, w1sTL, w1rTH, w1rTL);
    k_fuse_all<<<256, 512, 0, stream>>>(data, W3, W5, W31T, Beff1, Beff2,
                                        b12, b22, b31,
                                        wfTH, wfTL, bf, w1sTH, w1sTL, w1rTH, w1rTL, b1,
                                        hs, hrT, XT);
    k_adj<<<512, 256, 0, stream>>>(hs, hrT, w2, b2, gu, adjTG, dinv);

    const float* xnTs[3] = {XT, T0, T1};
    float*       outs[3] = {T0, T1, T2};
    for (int l = 0; l < 3; ++l){
        int aff = (l > 0);
        const float* gP = gamma + (l>0 ? (l-1)*HH : 0);
        const float* bP = beta  + (l>0 ? (l-1)*HH : 0);
        const float* aP = accf + (l>0 ? (l-1)*256 : 0);
        k_gnn<<<128, 512, 0, stream>>>(adjTG, xnTs[l], dinv, gP, bP, aP, aff,
            wHi + (size_t)l*16384, wLo + (size_t)l*16384,
            wHi + (size_t)(3+l)*16384, wLo + (size_t)(3+l)*16384,
            bl + (size_t)l*HH, outs[l], accf + (size_t)l*256);
    }
    k_head<<<BB, 128, 0, stream>>>(T0, T1, T2, accf, gamma, beta,
                                   wg, bg, we, be, wo, bo, out);
}

// Round 15
// 119.206 us; speedup vs baseline: 2.0278x; 1.0953x over previous
//
#include <hip/hip_runtime.h>
#include <math.h>

#define BB 32
#define SS 128
#define DIN 16
#define HH 128
#define NBSH (BB*SS*HH)   // 524288

typedef __attribute__((ext_vector_type(8))) short short8;
typedef __attribute__((ext_vector_type(4))) float vf4;

__device__ __forceinline__ unsigned short f2bf(float x){
    union { float f; unsigned int u; } v; v.f = x;
    unsigned int r = v.u + 0x7FFF + ((v.u >> 16) & 1);
    return (unsigned short)(r >> 16);
}
__device__ __forceinline__ float bf2f(unsigned short b){
    union { unsigned int u; float f; } v; v.u = ((unsigned int)b) << 16;
    return v.f;
}

// ============ K0: prep — composite conv weights + transposed bf16 splits ======
__global__ __launch_bounds__(256) void k_prep(
    const float* __restrict__ w12, const float* __restrict__ w22,
    const float* __restrict__ w31,
    const float* __restrict__ w11, const float* __restrict__ b11,
    const float* __restrict__ w21, const float* __restrict__ b21,
    const float* __restrict__ wl, const float* __restrict__ wr,
    const float* __restrict__ wf, const float* __restrict__ w1,
    float* __restrict__ W3, float* __restrict__ W5, float* __restrict__ W31T,
    float* __restrict__ Beff1, float* __restrict__ Beff2, float* __restrict__ accf,
    unsigned short* __restrict__ wHi, unsigned short* __restrict__ wLo,
    unsigned short* __restrict__ wfTH, unsigned short* __restrict__ wfTL,
    unsigned short* __restrict__ w1sTH, unsigned short* __restrict__ w1sTL,
    unsigned short* __restrict__ w1rTH, unsigned short* __restrict__ w1rTL)
{
    __shared__ float W12L[8*384];
    __shared__ float W22L[8*640];
    __shared__ float w11L[2048], w21L[2048], b11L[128], b21L[128];
    __shared__ float S[4096];
    int blk = blockIdx.x; int tid = threadIdx.x;

    if (blk < 16){
        int h0 = blk*8;
        for (int i = tid; i < 768; i += 256){
            int hl = i/96, o4 = i%96;
            *reinterpret_cast<float4*>(W12L + hl*384 + o4*4) =
                reinterpret_cast<const float4*>(w12)[(h0+hl)*96 + o4];
        }
        for (int i = tid; i < 1280; i += 256){
            int hl = i/160, o4 = i%160;
            *reinterpret_cast<float4*>(W22L + hl*640 + o4*4) =
                reinterpret_cast<const float4*>(w22)[(h0+hl)*160 + o4];
        }
        for (int i = tid; i < 512; i += 256)
            *reinterpret_cast<float4*>(w11L + i*4) = reinterpret_cast<const float4*>(w11)[i];
        for (int i = tid; i < 512; i += 256)
            *reinterpret_cast<float4*>(w21L + i*4) = reinterpret_cast<const float4*>(w21)[i];
        if (tid < 128){ b11L[tid] = b11[tid]; b21L[tid] = b21[tid]; }
        if (blk == 0){ for (int i = tid; i < 768; i += 256) accf[i] = 0.f; }
        __syncthreads();

        for (int T = tid; T < 1216; T += 256){
            if (T < 384){
                int hl = T/48, kd = T%48, k = kd>>4, d = kd&15;
                float a = 0.f;
                #pragma unroll 4
                for (int c = 0; c < HH; ++c) a = fmaf(W12L[hl*384 + c*3 + k], w11L[c*16 + d], a);
                W3[(k*16+d)*128 + h0+hl] = a;
            } else if (T < 1024){
                int tt = T-384, hl = tt/80, kd = tt%80, k = kd>>4, d = kd&15;
                float a = 0.f;
                #pragma unroll 4
                for (int c = 0; c < HH; ++c) a = fmaf(W22L[hl*640 + c*5 + k], w21L[c*16 + d], a);
                W5[(k*16+d)*128 + h0+hl] = a;
            } else if (T < 1048){
                int tt = T-1024, hl = tt/3, k = tt%3;
                float a = 0.f;
                #pragma unroll 4
                for (int c = 0; c < HH; ++c) a = fmaf(W12L[hl*384 + c*3 + k], b11L[c], a);
                Beff1[k*128 + h0+hl] = a;
            } else if (T < 1088){
                int tt = T-1048, hl = tt/5, k = tt%5;
                float a = 0.f;
                #pragma unroll 4
                for (int c = 0; c < HH; ++c) a = fmaf(W22L[hl*640 + c*5 + k], b21L[c], a);
                Beff2[k*128 + h0+hl] = a;
            } else {
                int tt = T-1088, hl = tt>>4, d = tt&15;
                W31T[d*128 + h0+hl] = w31[(h0+hl)*16 + d];
            }
        }
    } else if (blk < 40){
        int q = blk - 16;          // 0..23
        int h = tid & 127; int half = tid >> 7;
        for (int rl = half; rl < 32; rl += 2){
            int r = q*32 + rl;     // 0..767
            int m = r >> 7;
            int c = r & 127;
            const float* src = (m < 3) ? (wl + (size_t)m*16384) : (wr + (size_t)(m-3)*16384);
            float v = src[c*128 + h];
            unsigned short hi = f2bf(v);
            unsigned short lo = f2bf(v - bf2f(hi));
            wHi[(size_t)m*16384 + h*128 + c] = hi;
            wLo[(size_t)m*16384 + h*128 + c] = lo;
        }
    } else {
        // transpose + hi/lo split for wf (384x128) and w1 halves (128x128 each)
        int t2 = blk - 40;         // 0..19
        const float* src; unsigned short *dH, *dL; int kbase, rstride;
        if (t2 < 12){ src = wf + (size_t)t2*32*128; dH = wfTH; dL = wfTL; kbase = t2*32; rstride = 384; }
        else if (t2 < 16){ int c = t2-12; src = w1 + (size_t)c*32*128; dH = w1sTH; dL = w1sTL; kbase = c*32; rstride = 128; }
        else { int c = t2-16; src = w1 + 16384 + (size_t)c*32*128; dH = w1rTH; dL = w1rTL; kbase = c*32; rstride = 128; }
        for (int i = tid; i < 1024; i += 256)
            reinterpret_cast<float4*>(S)[i] = reinterpret_cast<const float4*>(src)[i];
        __syncthreads();
        for (int task = tid; task < 4096; task += 256){
            int h = task & 127, kl = task >> 7;   // kl 0..31
            float v = S[kl*128 + h];
            unsigned short hi = f2bf(v);
            dH[(size_t)h*rstride + kbase + kl] = hi;
            dL[(size_t)h*rstride + kbase + kl] = f2bf(v - bf2f(hi));
        }
    }
}

// ============ K1: conv fp32 -> MFMA fuse -> MFMA hs/hr (weights direct-global) =
// 256 blocks x 512 thr (8 waves); block = 16 rows of one batch b.
#define AHo 0
#define ALo 6272
#define xHo 12544
#define xLo 14720
__global__ __launch_bounds__(512) void k_fuse_all(
    const float* __restrict__ data,
    const float* __restrict__ W3, const float* __restrict__ W5,
    const float* __restrict__ W31T,
    const float* __restrict__ Beff1, const float* __restrict__ Beff2,
    const float* __restrict__ b12, const float* __restrict__ b22,
    const float* __restrict__ b31,
    const unsigned short* __restrict__ wfTH, const unsigned short* __restrict__ wfTL,
    const float* __restrict__ bf,
    const unsigned short* __restrict__ w1sTH, const unsigned short* __restrict__ w1sTL,
    const unsigned short* __restrict__ w1rTH, const unsigned short* __restrict__ w1rTL,
    const float* __restrict__ b1,
    float* __restrict__ hs, float* __restrict__ hrT, float* __restrict__ XT)
{
    __shared__ __align__(16) unsigned short pool[16896];   // 33.8 KB
    __shared__ __align__(16) float dinT[16*40];
    __shared__ float bfL[128], b1L[128];
    int blk = blockIdx.x; int row0 = blk*16;
    int b = row0 >> 7; int s0 = row0 & 127;
    int tid = threadIdx.x; int lane = tid & 63; int w = tid >> 6;      // 8 waves
    int h = tid & 127; int quarter = tid >> 7;
    int frow = lane & 15, fk = (lane >> 4) * 8;
    int ncol = w*16 + frow;

    for (int idx = tid; idx < 576; idx += 512){   // full 36-row halo
        int r = idx >> 4, d = idx & 15;
        int sp = s0 - 10 + r;
        dinT[d*40 + r] = (sp >= 0 && sp < SS) ? data[(b*SS+sp)*DIN + d] : 0.f;
    }
    if (tid < 128){ bfL[tid] = bf[tid]; b1L[tid] = b1[tid]; }
    __syncthreads();

    // ---- conv fp32: thread = channel h, rows quarter*4 .. +3 ----
    float a1[4] = {0,0,0,0}, a2[4] = {0,0,0,0}, a3[4] = {0,0,0,0};
    int rb = quarter*4;
    for (int d = 0; d < DIN; ++d){
        float w3v[3], w5v[5];
        #pragma unroll
        for (int k = 0; k < 3; ++k) w3v[k] = W3[(k*DIN+d)*HH + h];
        #pragma unroll
        for (int k = 0; k < 5; ++k) w5v[k] = W5[(k*DIN+d)*HH + h];
        float w31v = W31T[d*HH + h];
        const float4* qp = reinterpret_cast<const float4*>(dinT + d*40 + rb);
        float4 q0=qp[0],q1=qp[1],q2=qp[2],q3=qp[3],q4=qp[4],q5=qp[5];
        float qf[24] = {q0.x,q0.y,q0.z,q0.w, q1.x,q1.y,q1.z,q1.w,
                        q2.x,q2.y,q2.z,q2.w, q3.x,q3.y,q3.z,q3.w,
                        q4.x,q4.y,q4.z,q4.w, q5.x,q5.y,q5.z,q5.w};
        #pragma unroll
        for (int tp = 0; tp < 4; ++tp){
            #pragma unroll
            for (int k = 0; k < 3; ++k) a1[tp] = fmaf(qf[tp+3*k+7], w3v[k], a1[tp]);
            #pragma unroll
            for (int k = 0; k < 5; ++k) a2[tp] = fmaf(qf[tp+5*k], w5v[k], a2[tp]);
            a3[tp] = fmaf(qf[tp+10], w31v, a3[tp]);
        }
    }
    {
        float be1[3] = {Beff1[h], Beff1[HH+h], Beff1[2*HH+h]};
        float be2[5] = {Beff2[h], Beff2[HH+h], Beff2[2*HH+h], Beff2[3*HH+h], Beff2[4*HH+h]};
        float bv12 = b12[h], bv22 = b22[h], bv31 = b31[h];
        #pragma unroll
        for (int tp = 0; tp < 4; ++tp){
            int rl = rb + tp;
            int s = s0 + rl;
            float v1 = a1[tp] + bv12;
            #pragma unroll
            for (int k = 0; k < 3; ++k)
                if ((unsigned)(s + 3*k - 3) < SS) v1 += be1[k];
            float v2 = a2[tp] + bv22;
            #pragma unroll
            for (int k = 0; k < 5; ++k)
                if ((unsigned)(s + 5*k - 10) < SS) v2 += be2[k];
            float v3 = a3[tp] + bv31;
            unsigned short h1 = f2bf(v1), h2 = f2bf(v2), h3 = f2bf(v3);
            pool[AHo + rl*392 + h]        = h1;
            pool[AHo + rl*392 + 128 + h]  = h2;
            pool[AHo + rl*392 + 256 + h]  = h3;
            pool[ALo + rl*392 + h]        = f2bf(v1 - bf2f(h1));
            pool[ALo + rl*392 + 128 + h]  = f2bf(v2 - bf2f(h2));
            pool[ALo + rl*392 + 256 + h]  = f2bf(v3 - bf2f(h3));
        }
    }
    __syncthreads();

    // ---- fuse GEMM: A in LDS (stable), B fragments DIRECT from global ----
    vf4 facc; facc = 0.f;
    const unsigned short* wfh = wfTH + (size_t)ncol*384 + fk;
    const unsigned short* wfl = wfTL + (size_t)ncol*384 + fk;
    for (int ch = 0; ch < 12; ++ch){
        int ck0 = ch*32;
        short8 ah = *reinterpret_cast<const short8*>(pool + AHo + frow*392 + ck0 + fk);
        short8 al = *reinterpret_cast<const short8*>(pool + ALo + frow*392 + ck0 + fk);
        short8 bh = *reinterpret_cast<const short8*>(wfh + ck0);
        short8 bl = *reinterpret_cast<const short8*>(wfl + ck0);
        facc = __builtin_amdgcn_mfma_f32_16x16x32_bf16(ah, bh, facc, 0,0,0);
        facc = __builtin_amdgcn_mfma_f32_16x16x32_bf16(ah, bl, facc, 0,0,0);
        facc = __builtin_amdgcn_mfma_f32_16x16x32_bf16(al, bh, facc, 0,0,0);
        facc = __builtin_amdgcn_mfma_f32_16x16x32_bf16(al, bl, facc, 0,0,0);
    }
    // relu + bias -> xH/xL [m][k=h]
    {
        float bfv = bfL[ncol];
        #pragma unroll
        for (int r = 0; r < 4; ++r){
            int m = (lane>>4)*4 + r;
            float v = fmaxf(facc[r] + bfv, 0.f);
            unsigned short hi = f2bf(v);
            pool[xHo + m*136 + ncol] = hi;
            pool[xLo + m*136 + ncol] = f2bf(v - bf2f(hi));
        }
    }
    __syncthreads();
    // XT global write: x = hi+lo reconstruction
    for (int task = tid; task < 2048; task += 512){
        int m = task & 15, c = task >> 4;
        float v = bf2f(pool[xHo + m*136 + c]) + bf2f(pool[xLo + m*136 + c]);
        XT[((size_t)(b*HH + c))*SS + s0 + m] = v;
    }

    // ---- hs/hr GEMMs: x in LDS (stable), w1 fragments DIRECT from global ----
    vf4 as, ar; as = 0.f; ar = 0.f;
    for (int pass = 0; pass < 2; ++pass){
        const unsigned short* sH = (pass ? w1rTH : w1sTH) + (size_t)ncol*128 + fk;
        const unsigned short* sL = (pass ? w1rTL : w1sTL) + (size_t)ncol*128 + fk;
        vf4 acc; acc = 0.f;
        #pragma unroll
        for (int ch = 0; ch < 4; ++ch){
            int ck0 = ch*32;
            short8 ah = *reinterpret_cast<const short8*>(pool + xHo + frow*136 + ck0 + fk);
            short8 al = *reinterpret_cast<const short8*>(pool + xLo + frow*136 + ck0 + fk);
            short8 bh = *reinterpret_cast<const short8*>(sH + ck0);
            short8 bl = *reinterpret_cast<const short8*>(sL + ck0);
            acc = __builtin_amdgcn_mfma_f32_16x16x32_bf16(ah, bh, acc, 0,0,0);
            acc = __builtin_amdgcn_mfma_f32_16x16x32_bf16(ah, bl, acc, 0,0,0);
            acc = __builtin_amdgcn_mfma_f32_16x16x32_bf16(al, bh, acc, 0,0,0);
            acc = __builtin_amdgcn_mfma_f32_16x16x32_bf16(al, bl, acc, 0,0,0);
        }
        if (pass == 0) as = acc; else ar = acc;
    }
    {
        float b1v = b1L[ncol];
        #pragma unroll
        for (int r = 0; r < 4; ++r){
            int m = (lane>>4)*4 + r;
            hs[(size_t)(row0+m)*128 + ncol] = as[r];
            hrT[((size_t)(b*HH + ncol))*SS + s0 + m] = ar[r] + b1v;
        }
    }
}

// ============ K2: edge logits + argmax; emits adjT (bf16) + deginv ============
__global__ __launch_bounds__(256) void k_adj(
    const float* __restrict__ hs, const float* __restrict__ hrT,
    const float* __restrict__ w2, const float* __restrict__ b2,
    const float* __restrict__ gu, unsigned short* __restrict__ adjT,
    float* __restrict__ deginv)
{
    int blk = blockIdx.x; int b = blk >> 4; int j0 = (blk & 15) * 8;
    int tid = threadIdx.x; int i = tid & 127; int g = tid >> 7;
    __shared__ float hsL[8][128];
    __shared__ float w20L[128], w21L[128];
    __shared__ int degS[8];
    for (int idx = tid; idx < 1024; idx += 256){
        int jj = idx >> 7, h = idx & 127;
        hsL[jj][h] = hs[(size_t)(b*SS + j0 + jj)*HH + h];
    }
    if (tid < 128){ w20L[tid] = w2[tid*2]; w21L[tid] = w2[tid*2+1]; }
    if (tid < 8) degS[tid] = 0;
    __syncthreads();
    float d0[4] = {0,0,0,0}, d1[4] = {0,0,0,0};
    const float* hrb = hrT + (size_t)b*HH*SS + i;
    #pragma unroll 4
    for (int h = 0; h < 128; ++h){
        float hrv = hrb[(size_t)h*SS];
        float wa = w20L[h], wb = w21L[h];
        float r0 = fmaxf(hsL[g*4+0][h] + hrv, 0.f);
        float r1 = fmaxf(hsL[g*4+1][h] + hrv, 0.f);
        float r2 = fmaxf(hsL[g*4+2][h] + hrv, 0.f);
        float r3 = fmaxf(hsL[g*4+3][h] + hrv, 0.f);
        d0[0]=fmaf(r0,wa,d0[0]); d1[0]=fmaf(r0,wb,d1[0]);
        d0[1]=fmaf(r1,wa,d0[1]); d1[1]=fmaf(r1,wb,d1[1]);
        d0[2]=fmaf(r2,wa,d0[2]); d1[2]=fmaf(r2,wb,d1[2]);
        d0[3]=fmaf(r3,wa,d0[3]); d1[3]=fmaf(r3,wb,d1[3]);
    }
    float b20 = b2[0], b21 = b2[1];
    #pragma unroll
    for (int jj = 0; jj < 4; ++jj){
        int j = j0 + g*4 + jj;
        size_t e = (size_t)(b*SS + i)*SS + j;
        float2 uv = *reinterpret_cast<const float2*>(gu + e*2);
        float u0 = fminf(fmaxf(uv.x, 1e-6f), 0.999999f);
        float u1 = fminf(fmaxf(uv.y, 1e-6f), 0.999999f);
        float g0 = -logf(-logf(u0));
        float g1 = -logf(-logf(u1));
        float y0 = d0[jj] + b20 + g0;
        float y1 = d1[jj] + b21 + g1;
        bool av = (j > i) && (y0 >= y1);
        adjT[(size_t)(b*SS + j)*SS + i] = av ? (unsigned short)0x3F80 : (unsigned short)0;
        unsigned long long msk = __ballot(av);
        if ((tid & 63) == 0) atomicAdd(&degS[g*4+jj], (int)__popcll(msk));
    }
    __syncthreads();
    if (tid < 8) deginv[b*SS + j0 + tid] = 1.f / fmaxf((float)degS[tid], 1.f);
}

// ============ K3: MFMA GNN block, 512 thr; adjT + weights direct-global =======
#define AGGH 0
#define AGGL 4352
#define XH   8704
#define XL   17920
#define XNJH 27136
#define XNJL 31488
__global__ __launch_bounds__(512) void k_gnn(
    const unsigned short* __restrict__ adjT, const float* __restrict__ xnT,
    const float* __restrict__ deginv,
    const float* __restrict__ gammaP, const float* __restrict__ betaP,
    const float* __restrict__ accP, int aff,
    const unsigned short* __restrict__ wlH, const unsigned short* __restrict__ wlL,
    const unsigned short* __restrict__ wrH, const unsigned short* __restrict__ wrL,
    const float* __restrict__ bl,
    float* __restrict__ outT, float* __restrict__ accL)
{
    __shared__ __align__(16) unsigned short pool[35840];   // 71.7 KB
    __shared__ float2 scsh[128];
    __shared__ float dinvL[32];
    __shared__ float2 redS[128];
    __shared__ float blL[128];
    int blk = blockIdx.x; int b = blk >> 2; int j0 = (blk & 3) * 32;
    int tid = threadIdx.x; int lane = tid & 63; int w = tid >> 6;
    int frow = lane & 15, fk = (lane >> 4) * 8;

    if (tid < 128){
        if (aff){
            float2 s = reinterpret_cast<const float2*>(accP)[tid];
            float m = s.x * (1.f/4096.f);
            float var = fmaxf(s.y * (1.f/4096.f) - m*m, 0.f);
            float sc = gammaP[tid] / sqrtf(var + 1e-5f);
            scsh[tid] = make_float2(sc, betaP[tid] - m*sc);
        } else scsh[tid] = make_float2(1.f, 0.f);
        redS[tid] = make_float2(0.f, 0.f);
        blL[tid] = bl[tid];
    }
    if (tid < 32) dinvL[tid] = deginv[b*SS + j0 + tid];
    __syncthreads();   // fence before any scsh read

    // ---- agg: C[m=j 32][n=h 128]; A = adjT DIRECT global; B = xn_eff in LDS --
    int mt = w & 1, ntb = (w >> 1) * 2;
    const unsigned short* adjrow = adjT + ((size_t)(b*SS + j0 + mt*16 + frow))*SS + fk;
    vf4 acc[2]; acc[0]=0.f; acc[1]=0.f;
    for (int cs = 0; cs < 2; ++cs){
        for (int task = tid; task < 2048; task += 512){
            int hh = task >> 4, q = task & 15;
            float4 v = *reinterpret_cast<const float4*>(
                xnT + ((size_t)(b*HH + hh))*SS + cs*64 + q*4);
            float2 ss = scsh[hh];
            float e0 = fmaf(v.x, ss.x, ss.y), e1 = fmaf(v.y, ss.x, ss.y);
            float e2 = fmaf(v.z, ss.x, ss.y), e3 = fmaf(v.w, ss.x, ss.y);
            unsigned short h0 = f2bf(e0), h1 = f2bf(e1), h2 = f2bf(e2), h3 = f2bf(e3);
            unsigned int hA = (unsigned int)h0 | ((unsigned int)h1 << 16);
            unsigned int hB = (unsigned int)h2 | ((unsigned int)h3 << 16);
            unsigned short l0 = f2bf(e0 - bf2f(h0)), l1 = f2bf(e1 - bf2f(h1));
            unsigned short l2 = f2bf(e2 - bf2f(h2)), l3 = f2bf(e3 - bf2f(h3));
            unsigned int lA = (unsigned int)l0 | ((unsigned int)l1 << 16);
            unsigned int lB = (unsigned int)l2 | ((unsigned int)l3 << 16);
            *reinterpret_cast<uint2*>(pool + XH + hh*72 + q*4) = make_uint2(hA, hB);
            *reinterpret_cast<uint2*>(pool + XL + hh*72 + q*4) = make_uint2(lA, lB);
        }
        __syncthreads();
        #pragma unroll
        for (int ks = 0; ks < 2; ++ks){
            short8 af = *reinterpret_cast<const short8*>(adjrow + cs*64 + ks*32);
            #pragma unroll
            for (int ntl = 0; ntl < 2; ++ntl){
                int nt = ntb + ntl;
                short8 bh = *reinterpret_cast<const short8*>(
                    pool + XH + (nt*16 + frow)*72 + ks*32 + fk);
                short8 bo = *reinterpret_cast<const short8*>(
                    pool + XL + (nt*16 + frow)*72 + ks*32 + fk);
                acc[ntl] = __builtin_amdgcn_mfma_f32_16x16x32_bf16(af, bh, acc[ntl], 0, 0, 0);
                acc[ntl] = __builtin_amdgcn_mfma_f32_16x16x32_bf16(af, bo, acc[ntl], 0, 0, 0);
            }
        }
        __syncthreads();
    }
    // agg epilogue -> AGGH/AGGL [j][c=h]; stage xnJ [j][c] hi/lo (first 256 thr)
    #pragma unroll
    for (int ntl = 0; ntl < 2; ++ntl){
        int hh = (ntb + ntl)*16 + frow;
        #pragma unroll
        for (int r = 0; r < 4; ++r){
            int jl = mt*16 + (lane>>4)*4 + r;
            float v = acc[ntl][r] * dinvL[jl];
            unsigned short hi = f2bf(v);
            pool[AGGH + jl*136 + hh] = hi;
            pool[AGGL + jl*136 + hh] = f2bf(v - bf2f(hi));
        }
    }
    if (tid < 256){
        int jg = tid >> 5, cg = tid & 31;
        float mv[4][4];
        #pragma unroll
        for (int e = 0; e < 4; ++e){
            float4 v = *reinterpret_cast<const float4*>(
                xnT + ((size_t)(b*HH + cg*4 + e))*SS + j0 + jg*4);
            float2 ss = scsh[cg*4 + e];
            mv[e][0]=fmaf(v.x,ss.x,ss.y); mv[e][1]=fmaf(v.y,ss.x,ss.y);
            mv[e][2]=fmaf(v.z,ss.x,ss.y); mv[e][3]=fmaf(v.w,ss.x,ss.y);
        }
        #pragma unroll
        for (int f = 0; f < 4; ++f){
            int jl = jg*4 + f;
            unsigned short h0=f2bf(mv[0][f]), h1=f2bf(mv[1][f]), h2=f2bf(mv[2][f]), h3=f2bf(mv[3][f]);
            unsigned int a0 = (unsigned int)h0 | ((unsigned int)h1<<16);
            unsigned int a1v = (unsigned int)h2 | ((unsigned int)h3<<16);
            unsigned short l0=f2bf(mv[0][f]-bf2f(h0)), l1=f2bf(mv[1][f]-bf2f(h1));
            unsigned short l2=f2bf(mv[2][f]-bf2f(h2)), l3=f2bf(mv[3][f]-bf2f(h3));
            unsigned int b0 = (unsigned int)l0 | ((unsigned int)l1<<16);
            unsigned int b1v = (unsigned int)l2 | ((unsigned int)l3<<16);
            *reinterpret_cast<uint2*>(pool + XNJH + jl*136 + cg*4) = make_uint2(a0, a1v);
            *reinterpret_cast<uint2*>(pool + XNJL + jl*136 + cg*4) = make_uint2(b0, b1v);
        }
    }
    __syncthreads();

    // ---- lin: C[m=h 128][n=j 32]; A = weights DIRECT global; B in LDS --------
    vf4 lacc[2]; lacc[0]=0.f; lacc[1]=0.f;
    int hh_a = w*16 + frow;
    const unsigned short* wlh = wlH + (size_t)hh_a*128 + fk;
    const unsigned short* wll = wlL + (size_t)hh_a*128 + fk;
    const unsigned short* wrh = wrH + (size_t)hh_a*128 + fk;
    const unsigned short* wrl = wrL + (size_t)hh_a*128 + fk;
    #pragma unroll
    for (int ck = 0; ck < 4; ++ck){
        int ck0 = ck*32;
        #pragma unroll
        for (int mat = 0; mat < 2; ++mat){
            short8 ah = *reinterpret_cast<const short8*>((mat ? wrh : wlh) + ck0);
            short8 al = *reinterpret_cast<const short8*>((mat ? wrl : wll) + ck0);
            int Bh = mat ? XNJH : AGGH;
            int Bl = mat ? XNJL : AGGL;
            #pragma unroll
            for (int ntl = 0; ntl < 2; ++ntl){
                short8 bh = *reinterpret_cast<const short8*>(
                    pool + Bh + (ntl*16 + frow)*136 + ck0 + fk);
                short8 bo = *reinterpret_cast<const short8*>(
                    pool + Bl + (ntl*16 + frow)*136 + ck0 + fk);
                lacc[ntl] = __builtin_amdgcn_mfma_f32_16x16x32_bf16(ah, bh, lacc[ntl], 0,0,0);
                lacc[ntl] = __builtin_amdgcn_mfma_f32_16x16x32_bf16(ah, bo, lacc[ntl], 0,0,0);
                lacc[ntl] = __builtin_amdgcn_mfma_f32_16x16x32_bf16(al, bh, lacc[ntl], 0,0,0);
            }
        }
    }
    // epilogue: bias, store, BN partials via 16-lane shfl reduce (wave-disjoint hh)
    #pragma unroll
    for (int ntl = 0; ntl < 2; ++ntl){
        #pragma unroll
        for (int r = 0; r < 4; ++r){
            int hh = w*16 + (lane>>4)*4 + r;
            int jl = ntl*16 + (lane & 15);
            float v = lacc[ntl][r] + blL[hh];
            outT[((size_t)(b*HH + hh))*SS + j0 + jl] = v;
            float s1 = v, s2 = v*v;
            #pragma unroll
            for (int off = 1; off < 16; off <<= 1){
                s1 += __shfl_xor(s1, off, 64);
                s2 += __shfl_xor(s2, off, 64);
            }
            if ((lane & 15) == 0){ redS[hh].x += s1; redS[hh].y += s2; }
        }
    }
    __syncthreads();
    if (tid < 128){
        atomicAdd(&accL[2*tid],   redS[tid].x);
        atomicAdd(&accL[2*tid+1], redS[tid].y);
    }
}

// ============ K4: head ========================================================
__global__ __launch_bounds__(128) void k_head(
    const float* __restrict__ t0, const float* __restrict__ t1,
    const float* __restrict__ t2, const float* __restrict__ accf,
    const float* __restrict__ gamma, const float* __restrict__ beta,
    const float* __restrict__ wg, const float* __restrict__ bg,
    const float* __restrict__ we, const float* __restrict__ be,
    const float* __restrict__ wo, const float* __restrict__ bo,
    float* __restrict__ out)
{
    int b = blockIdx.x; int t = threadIdx.x;
    __shared__ float xw[HH];
    const float* outs[3] = {t0, t1, t2};
    float a = bg[0];
    #pragma unroll
    for (int l = 0; l < 3; ++l){
        float2 s = reinterpret_cast<const float2*>(accf)[l*128 + t];
        float m = s.x * (1.f/4096.f);
        float var = fmaxf(s.y * (1.f/4096.f) - m*m, 0.f);
        float sc = gamma[l*128+t] / sqrtf(var + 1e-5f);
        float sh = beta[l*128+t] - m*sc;
        float val = fmaf(outs[l][((size_t)(b*HH + t))*SS + SS-1], sc, sh);
        a = fmaf(val, wg[l], a);
    }
    xw[t] = fmaxf(a, 0.f);
    __syncthreads();
    if (t < 64){
        float acc = be[t];
        for (int h = 0; h < HH; ++h) acc = fmaf(xw[h], we[h*64 + t], acc);
        float h2 = fmaxf(acc, 0.f);
        float r = h2 * wo[t];
        #pragma unroll
        for (int off = 32; off; off >>= 1) r += __shfl_down(r, off, 64);
        if (t == 0) out[b] = r + bo[0];
    }
}

// ==============================================================================
extern "C" void kernel_launch(void* const* d_in, const int* in_sizes, int n_in,
                              void* d_out, int out_size, void* d_ws, size_t ws_size,
                              hipStream_t stream)
{
    const float* data = (const float*)d_in[0];
    const float* gu   = (const float*)d_in[1];
    const float* w11  = (const float*)d_in[2];
    const float* b11  = (const float*)d_in[3];
    const float* w12  = (const float*)d_in[4];
    const float* b12  = (const float*)d_in[5];
    const float* w21  = (const float*)d_in[6];
    const float* b21  = (const float*)d_in[7];
    const float* w22  = (const float*)d_in[8];
    const float* b22  = (const float*)d_in[9];
    const float* w31  = (const float*)d_in[10];
    const float* b31  = (const float*)d_in[11];
    const float* wf   = (const float*)d_in[12];
    const float* bf   = (const float*)d_in[13];
    const float* w1   = (const float*)d_in[14];
    const float* b1   = (const float*)d_in[15];
    const float* w2   = (const float*)d_in[16];
    const float* b2   = (const float*)d_in[17];
    const float* wl   = (const float*)d_in[18];
    const float* bl   = (const float*)d_in[19];
    const float* wr   = (const float*)d_in[20];
    const float* gamma= (const float*)d_in[21];
    const float* beta = (const float*)d_in[22];
    const float* wg   = (const float*)d_in[23];
    const float* bg   = (const float*)d_in[24];
    const float* we   = (const float*)d_in[25];
    const float* be   = (const float*)d_in[26];
    const float* wo   = (const float*)d_in[27];
    const float* bo   = (const float*)d_in[28];
    float* out = (float*)d_out;

    float* ws = (float*)d_ws;
    float* hs   = ws;                          // NBSH
    float* hrT  = ws + (size_t)NBSH;
    float* XT   = ws + (size_t)2*NBSH;
    float* T0   = ws + (size_t)3*NBSH;
    float* T1   = ws + (size_t)4*NBSH;
    float* T2   = ws + (size_t)5*NBSH;
    float* G    = ws + (size_t)6*NBSH;
    float* W3    = G;                          // 6144
    float* W5    = G + 6144;                   // 10240
    float* W31T  = G + 16384;                  // 2048
    float* Beff1 = G + 18432;                  // 384
    float* Beff2 = G + 18816;                  // 640
    float* accf  = G + 19456;                  // 768
    float* dinv  = G + 20224;                  // 4096
    unsigned short* adjTG = (unsigned short*)(G + 24320);           // 262144 fl
    unsigned short* wHi   = (unsigned short*)(G + 286464);          // 49152 fl
    unsigned short* wLo   = (unsigned short*)(G + 335616);          // 49152 fl
    unsigned short* wfTH  = (unsigned short*)(G + 384768);          // 24576 fl
    unsigned short* wfTL  = (unsigned short*)(G + 409344);
    unsigned short* w1sTH = (unsigned short*)(G + 433920);          // 8192 fl
    unsigned short* w1sTL = (unsigned short*)(G + 442112);
    unsigned short* w1rTH = (unsigned short*)(G + 450304);
    unsigned short* w1rTL = (unsigned short*)(G + 458496);

    k_prep<<<60, 256, 0, stream>>>(w12, w22, w31, w11, b11, w21, b21, wl, wr,
                                   wf, w1,
                                   W3, W5, W31T, Beff1, Beff2, accf, wHi, wLo,
                                   wfTH, wfTL, w1sTH, w1sTL, w1rTH, w1rTL);
    k_fuse_all<<<256, 512, 0, stream>>>(data, W3, W5, W31T, Beff1, Beff2,
                                        b12, b22, b31,
                                        wfTH, wfTL, bf, w1sTH, w1sTL, w1rTH, w1rTL, b1,
                                        hs, hrT, XT);
    k_adj<<<512, 256, 0, stream>>>(hs, hrT, w2, b2, gu, adjTG, dinv);

    const float* xnTs[3] = {XT, T0, T1};
    float*       outs[3] = {T0, T1, T2};
    for (int l = 0; l < 3; ++l){
        int aff = (l > 0);
        const float* gP = gamma + (l>0 ? (l-1)*HH : 0);
        const float* bP = beta  + (l>0 ? (l-1)*HH : 0);
        const float* aP = accf + (l>0 ? (l-1)*256 : 0);
        k_gnn<<<128, 512, 0, stream>>>(adjTG, xnTs[l], dinv, gP, bP, aP, aff,
            wHi + (size_t)l*16384, wLo + (size_t)l*16384,
            wHi + (size_t)(3+l)*16384, wLo + (size_t)(3+l)*16384,
            bl + (size_t)l*HH, outs[l], accf + (size_t)l*256);
    }
    k_head<<<BB, 128, 0, stream>>>(T0, T1, T2, accf, gamma, beta,
                                   wg, bg, we, be, wo, bo, out);
}